// Round 1
// baseline (417.595 us; speedup 1.0000x reference)
//
#include <hip/hip_runtime.h>
#include <cstdint>

#define N_ 16
#define C_ 256
#define H_ 64
#define W_ 64
#define L_ 4096          // H*W
#define K_ 32
#define CL_ (C_*L_)      // 1048576
#define KL_ (K_*L_)      // 131072
#define KC_ (K_*C_)      // 8192

typedef __attribute__((ext_vector_type(8))) short short8;   // 8 bf16 (4 VGPRs)
typedef __attribute__((ext_vector_type(4))) float f32x4;    // MFMA C/D frag

__device__ __forceinline__ unsigned short f2bf(float x) {   // RNE fp32->bf16
    unsigned int u = __float_as_uint(x);
    u += 0x7fffu + ((u >> 16) & 1u);
    return (unsigned short)(u >> 16);
}
__device__ __forceinline__ unsigned int pack2(float a, float b) {
    return (unsigned int)f2bf(a) | ((unsigned int)f2bf(b) << 16);
}

// ---------- K1: fused rinv + xn(bf16) transposed to (n,l,c) ----------
__global__ __launch_bounds__(256) void k_prep(
    const float* __restrict__ f, float* __restrict__ rinv,
    unsigned short* __restrict__ xnb)
{
    __shared__ float tile[256 * 34];            // [c][l], stride 34 (conflict-free)
    __shared__ float ssred[8 * 33];
    __shared__ float rbuf[32];
    int bid = blockIdx.x;
    int n = bid >> 7;
    int l0 = (bid & 127) << 5;
    int tid = threadIdx.x;
    int l = tid & 31, cb = tid >> 5;            // cb 0..7
    const float* fp = f + (size_t)n * CL_ + l0 + l;
    float ss = 0.f;
#pragma unroll
    for (int i = 0; i < 32; ++i) {
        int c = (cb << 5) + i;
        float v = fp[(size_t)c * L_];
        tile[c * 34 + l] = v;
        ss = fmaf(v, v, ss);
    }
    ssred[cb * 33 + l] = ss;
    __syncthreads();
    if (tid < 32) {
        float s = 0.f;
#pragma unroll
        for (int j = 0; j < 8; ++j) s += ssred[j * 33 + tid];
        float ri = 1.0f / fmaxf(sqrtf(s), 1e-12f);
        rinv[n * L_ + l0 + tid] = ri;
        rbuf[tid] = ri;
    }
    __syncthreads();
    float ri = rbuf[l];
    unsigned short* op = xnb + ((size_t)n * L_ + l0 + l) * C_ + (cb << 5);
#pragma unroll
    for (int g = 0; g < 4; ++g) {
        unsigned int pk[4];
#pragma unroll
        for (int d = 0; d < 4; ++d) {
            int c = (cb << 5) + (g << 3) + (d << 1);
            pk[d] = pack2(tile[c * 34 + l] * ri, tile[(c + 1) * 34 + l] * ri);
        }
        *(uint4*)(op + (g << 3)) = make_uint4(pk[0], pk[1], pk[2], pk[3]);
    }
}

// ---------- K2: repack conv weights -> wb[t][k][c] bf16 ----------
__global__ __launch_bounds__(256) void k_wpack(const float* __restrict__ w, unsigned short* __restrict__ wb) {
    int i = blockIdx.x * 256 + threadIdx.x;     // 73728
    int t = i >> 13;
    int k = (i >> 8) & 31;
    int c = i & 255;
    wb[i] = f2bf(w[k * 2304 + c * 9 + t]);
}

// ---------- generic 256x256 weight pack (row stride in floats) ----------
__global__ __launch_bounds__(256) void k_wpack2(const float* __restrict__ w, int stride,
                                                unsigned short* __restrict__ wb) {
    int i = blockIdx.x * 256 + threadIdx.x;     // 65536
    int co = i >> 8, ci = i & 255;
    wb[i] = f2bf(w[(size_t)co * stride + ci]);
}

// ---------- K3: MFMA 3x3 conv + fused softmax + fused ssum ----------
// grid: 1024 blocks x 256 threads. Swizzle: (n,y) = (bid&15, bid>>4) so all 64
// row-blocks of image n sit on XCD n&7 -> halo rows (read 3x) become L2 hits.
// Prefetch distance 2: staged xnb loads for chunk i+2 issued at chunk i ->
// ~2 MFMA-phases of latency hiding instead of ~1.
// LDS px-stride padded to 40 ushorts (80 B): banks spread 2-way (free)
__global__ __launch_bounds__(256, 4) void k_conv(
    const unsigned short* __restrict__ xnb, const unsigned short* __restrict__ wb,
    const float* __restrict__ bias, float* __restrict__ sa, float* __restrict__ ssum)
{
    __shared__ __align__(16) unsigned short lsB[2][3 * 66 * 40];   // 2 x 15840 B
    __shared__ float sred[4][32];
    int bid = blockIdx.x;
    int n = bid & 15, y = bid >> 4;             // XCD-locality swizzle
    int tid = threadIdx.x;
    int wv = tid >> 6, lane = tid & 63;
    int r = lane & 15, quad = lane >> 4;
    int pxw = (wv << 4) + r;                    // this lane's output x
    const unsigned short* xb = xnb + (size_t)n * CL_;

    // staging plan: 3 rows x 66 px x 4 quads = 792 uint4 items, 3-4 per thread
    const unsigned short* sptr[4];
    int sidx[4];
    bool svalid[4];
    int scnt = (tid < 24) ? 4 : 3;
#pragma unroll
    for (int k = 0; k < 4; ++k) {
        int j = tid + (k << 8);
        int row = j / 264; if (row > 2) row = 2;
        int rem = j - row * 264;
        int px = rem >> 2, q = rem & 3;
        int yy = y + row - 1, xx = px - 1;
        bool ok = ((unsigned)yy < 64u) && ((unsigned)xx < 64u);
        int yc = ok ? yy : 0, xc = ok ? xx : 0;
        sptr[k] = xb + (((size_t)(yc << 6) + xc) << 8) + (q << 3);
        svalid[k] = ok;
        sidx[k] = (row * 66 + px) * 40 + (q << 3);
    }
    const uint4 z4 = make_uint4(0, 0, 0, 0);
    uint4 preA[4], preB[4];
#pragma unroll
    for (int k = 0; k < 4; ++k)
        preA[k] = (k < scnt && svalid[k]) ? *(const uint4*)sptr[k] : z4;          // chunk 0
#pragma unroll
    for (int k = 0; k < 4; ++k)
        preB[k] = (k < scnt && svalid[k]) ? *(const uint4*)(sptr[k] + 32) : z4;   // chunk 1

    f32x4 acc0 = (f32x4){0.f, 0.f, 0.f, 0.f};
    f32x4 acc1 = (f32x4){0.f, 0.f, 0.f, 0.f};
#pragma unroll
    for (int i = 0; i < 8; ++i) {
        int c0 = i << 5;
        unsigned short* buf = lsB[i & 1];
#pragma unroll
        for (int k = 0; k < 4; ++k)
            if (k < scnt) *(uint4*)(buf + sidx[k]) = preA[k];
        __syncthreads();                        // single barrier/chunk (dbuf proof holds)
#pragma unroll
        for (int k = 0; k < 4; ++k) preA[k] = preB[k];   // renamed away by full unroll
        if (i < 6) {
#pragma unroll
            for (int k = 0; k < 4; ++k)
                preB[k] = (k < scnt && svalid[k]) ? *(const uint4*)(sptr[k] + ((i + 2) << 5)) : z4;
        }
        const unsigned short* wchunk = wb + c0 + (quad << 3);
#pragma unroll
        for (int t = 0; t < 9; ++t) {
            int dy = t / 3, dx = t % 3;
            short8 B  = *(const short8*)(buf + (dy * 66 + pxw + dx) * 40 + (quad << 3));
            short8 A0 = *(const short8*)(wchunk + t * 8192 + r * 256);
            short8 A1 = *(const short8*)(wchunk + t * 8192 + (16 + r) * 256);
            acc0 = __builtin_amdgcn_mfma_f32_16x16x32_bf16(A0, B, acc0, 0, 0, 0);
            acc1 = __builtin_amdgcn_mfma_f32_16x16x32_bf16(A1, B, acc1, 0, 0, 0);
        }
    }
    // bias + softmax over k (32 values per px: 4 quads x 8 regs)
    float4 b0 = *(const float4*)(bias + (quad << 2));
    float4 b1 = *(const float4*)(bias + 16 + (quad << 2));
    float v[8];
    v[0] = acc0[0] + b0.x; v[1] = acc0[1] + b0.y; v[2] = acc0[2] + b0.z; v[3] = acc0[3] + b0.w;
    v[4] = acc1[0] + b1.x; v[5] = acc1[1] + b1.y; v[6] = acc1[2] + b1.z; v[7] = acc1[3] + b1.w;
    float mx = v[0];
#pragma unroll
    for (int j = 1; j < 8; ++j) mx = fmaxf(mx, v[j]);
    mx = fmaxf(mx, __shfl_xor(mx, 16));
    mx = fmaxf(mx, __shfl_xor(mx, 32));
    float s = 0.f;
#pragma unroll
    for (int j = 0; j < 8; ++j) { v[j] = __expf(v[j] - mx); s += v[j]; }
    s += __shfl_xor(s, 16);
    s += __shfl_xor(s, 32);
    float rs = 1.0f / s;
    float sv8[8];
#pragma unroll
    for (int j = 0; j < 8; ++j) sv8[j] = v[j] * rs;
    int l = (y << 6) + pxw;
    float* sp = sa + (size_t)n * KL_ + l;
#pragma unroll
    for (int j = 0; j < 4; ++j) {
        sp[(size_t)((quad << 2) + j) * L_] = sv8[j];
        sp[(size_t)(16 + (quad << 2) + j) * L_] = sv8[4 + j];
    }
    // fused ssum: reduce over the wave's 16 px (lane bits 0-3), combine waves in LDS
#pragma unroll
    for (int j = 0; j < 8; ++j) {
        float a = sv8[j];
        a += __shfl_xor(a, 1); a += __shfl_xor(a, 2);
        a += __shfl_xor(a, 4); a += __shfl_xor(a, 8);
        sv8[j] = a;
    }
    if (r == 0) {
#pragma unroll
        for (int j = 0; j < 4; ++j) {
            sred[wv][(quad << 2) + j] = sv8[j];
            sred[wv][16 + (quad << 2) + j] = sv8[4 + j];
        }
    }
    __syncthreads();
    if (tid < 32) {
        float t = sred[0][tid] + sred[1][tid] + sred[2][tid] + sred[3][tid];
        atomicAdd(ssum + n * K_ + tid, t);
    }
}

// ---------- K5: up[n,k,c] += sum_l sa[n,k,l] * xn[n,c,l] ----------
__global__ __launch_bounds__(256) void k_einsum(
    const float* __restrict__ f, const float* __restrict__ rinv,
    const float* __restrict__ sa, float* __restrict__ up)
{
    __shared__ float xn_s[C_ * 33];
    __shared__ float sa_s[K_ * 32];
    int bid = blockIdx.x;                       // 512
    int n = bid >> 5;
    int l0 = (bid & 31) << 7;
    int tid = threadIdx.x;
    int kq = tid >> 5, cq = tid & 31;
    float acc[4][8];
#pragma unroll
    for (int i = 0; i < 4; ++i)
#pragma unroll
        for (int j = 0; j < 8; ++j) acc[i][j] = 0.f;

    for (int ch = 0; ch < 4; ++ch) {
        int lc = l0 + (ch << 5);
        __syncthreads();
        {
            int crow = tid >> 3, lq = (tid & 7) << 2;
#pragma unroll
            for (int p = 0; p < 8; ++p) {
                int c = (p << 5) + crow;
                float4 f4 = *(const float4*)(f + (size_t)n * CL_ + (size_t)c * L_ + lc + lq);
                float4 r4 = *(const float4*)(rinv + n * L_ + lc + lq);
                float* d = xn_s + c * 33 + lq;
                d[0] = f4.x * r4.x; d[1] = f4.y * r4.y; d[2] = f4.z * r4.z; d[3] = f4.w * r4.w;
            }
        }
        {
            int k = tid >> 3, lq = (tid & 7) << 2;
            float4 a4 = *(const float4*)(sa + (size_t)n * KL_ + (size_t)k * L_ + lc + lq);
            *(float4*)(sa_s + (k << 5) + lq) = a4;
        }
        __syncthreads();
#pragma unroll 4
        for (int l = 0; l < 32; ++l) {
            float sv[4], xv[8];
#pragma unroll
            for (int i = 0; i < 4; ++i) sv[i] = sa_s[((kq << 2) + i) * 32 + l];
#pragma unroll
            for (int j = 0; j < 8; ++j) xv[j] = xn_s[(cq + (j << 5)) * 33 + l];
#pragma unroll
            for (int i = 0; i < 4; ++i)
#pragma unroll
                for (int j = 0; j < 8; ++j) acc[i][j] = fmaf(sv[i], xv[j], acc[i][j]);
        }
    }
    float* upp = up + (size_t)n * KC_;
#pragma unroll
    for (int i = 0; i < 4; ++i)
#pragma unroll
        for (int j = 0; j < 8; ++j)
            atomicAdd(upp + ((kq << 2) + i) * C_ + cq + (j << 5), acc[i][j]);
}

// ---------- K6: subtract centroid term, l2norm rows, record row sumsq ----------
__global__ __launch_bounds__(256) void k_rowfix(
    const float* __restrict__ up, const float* __restrict__ ssum,
    const float* __restrict__ cent, float* __restrict__ upn, float* __restrict__ rowss)
{
    __shared__ float red[256];
    int bid = blockIdx.x;                       // n*K + k
    int k = bid & 31;
    float sv = ssum[bid];
    float v = up[(size_t)bid * C_ + threadIdx.x] - sv * cent[k * C_ + threadIdx.x];
    red[threadIdx.x] = v * v; __syncthreads();
    for (int st = 128; st > 0; st >>= 1) {
        if (threadIdx.x < st) red[threadIdx.x] += red[threadIdx.x + st];
        __syncthreads();
    }
    float ss = red[0];
    float ri = 1.0f / fmaxf(sqrtf(ss), 1e-12f);
    upn[(size_t)bid * C_ + threadIdx.x] = v * ri;
    if (threadIdx.x == 0) rowss[bid] = ss * ri * ri;
}

// ---------- K7: global l2norm + FC, one block per output channel c ----------
__global__ __launch_bounds__(256) void k_fc(
    const float* __restrict__ upn, const float* __restrict__ rowss,
    const float* __restrict__ w, const float* __restrict__ b,
    float* __restrict__ upvec)
{
    __shared__ float rnb[16];
    __shared__ float red[16][5];
    int c = blockIdx.x;                         // 256
    int tid = threadIdx.x;
    int wv = tid >> 6, lane = tid & 63;
    if (tid < 16) {
        float ts = 0.f;
#pragma unroll
        for (int k = 0; k < K_; ++k) ts += rowss[(tid << 5) + k];
        rnb[tid] = 1.0f / fmaxf(sqrtf(ts), 1e-12f);
    }
    float acc[16];
#pragma unroll
    for (int n = 0; n < 16; ++n) acc[n] = 0.f;
    const float* wr = w + (size_t)c * KC_;
#pragma unroll
    for (int g = 0; g < 8; ++g) {
        int kc = (g << 10) + (tid << 2);
        float4 w4 = *(const float4*)(wr + kc);
#pragma unroll
        for (int n = 0; n < 16; ++n) {
            float4 u4 = *(const float4*)(upn + n * KC_ + kc);
            acc[n] += w4.x * u4.x + w4.y * u4.y + w4.z * u4.z + w4.w * u4.w;
        }
    }
#pragma unroll
    for (int n = 0; n < 16; ++n) {
        float a = acc[n];
#pragma unroll
        for (int s = 1; s < 64; s <<= 1) a += __shfl_xor(a, s);
        if (lane == 0) red[n][wv] = a;
    }
    __syncthreads();
    if (tid < 16) {
        float v = red[tid][0] + red[tid][1] + red[tid][2] + red[tid][3];
        upvec[tid * C_ + c] = v * rnb[tid] + b[c];
    }
}

// ---------- K8: t1up[n,co] = t1_w[co,256:512] . upvec[n,:] + t1_b[co] ----------
__global__ __launch_bounds__(256) void k_t1up(
    const float* __restrict__ upvec, const float* __restrict__ t1w,
    const float* __restrict__ t1b, float* __restrict__ t1up)
{
    __shared__ float wld[256];
    int co = blockIdx.x;                        // 256
    int tid = threadIdx.x;
    wld[tid] = t1w[(size_t)co * 512 + 256 + tid];
    __syncthreads();
    int n = tid >> 4, s = tid & 15;
    float a = 0.f;
#pragma unroll
    for (int i = 0; i < 16; ++i)
        a += wld[s + (i << 4)] * upvec[n * C_ + s + (i << 4)];
#pragma unroll
    for (int st = 1; st < 16; st <<= 1) a += __shfl_xor(a, st);
    if (s == 0) t1up[n * C_ + co] = a + t1b[co];
}

// ---------- K9: MFMA gemm1, issue-early/pack-late pipelined LDS-staged B ----------
// hb[n,l,co] = bf16(relu(f[n,:,l]·t1wb[co,:] + t1up[n,co]))
__global__ __launch_bounds__(256) void k_gemm1(
    const float* __restrict__ f, const unsigned short* __restrict__ wb,
    const float* __restrict__ t1up, unsigned short* __restrict__ hb)
{
    __shared__ __align__(16) unsigned int lsB[2][128 * 20];     // px stride 20 uints (padded)
    int bid = blockIdx.x;                       // 1024 = n(16) x px_b(32) x co_b(2)
    int co_b = bid & 1, px_b = (bid >> 1) & 31, n = bid >> 6;
    int l0 = px_b << 7;
    int tid = threadIdx.x;
    int wv = tid >> 6, lane = tid & 63;
    int r = lane & 15, quad = lane >> 4;
    int pxl = (wv >> 1) << 6;                   // block-local px base for wave
    int co0 = (co_b << 7) + ((wv & 1) << 6);
    const float* fb_ = f + (size_t)n * CL_ + l0;
    int c2 = tid & 15, pxg = tid >> 4;          // item 0; item 1 = +256 -> pxg+16

    float4 ra[2], rb[2];
#pragma unroll
    for (int k2 = 0; k2 < 2; ++k2) {
        const float* s0 = fb_ + (size_t)(c2 << 1) * L_ + ((pxg + (k2 << 4)) << 2);
        ra[k2] = *(const float4*)s0;
        rb[k2] = *(const float4*)(s0 + L_);
    }
    unsigned int pk[2][4];
#pragma unroll
    for (int k2 = 0; k2 < 2; ++k2) {
        pk[k2][0] = pack2(ra[k2].x, rb[k2].x); pk[k2][1] = pack2(ra[k2].y, rb[k2].y);
        pk[k2][2] = pack2(ra[k2].z, rb[k2].z); pk[k2][3] = pack2(ra[k2].w, rb[k2].w);
    }
    f32x4 acc[4][4];
#pragma unroll
    for (int i = 0; i < 4; ++i)
#pragma unroll
        for (int j = 0; j < 4; ++j) acc[i][j] = (f32x4){0.f, 0.f, 0.f, 0.f};

#pragma unroll
    for (int i = 0; i < 8; ++i) {
        int c0 = i << 5;
        unsigned int* buf = lsB[i & 1];
#pragma unroll
        for (int k2 = 0; k2 < 2; ++k2) {
            int base = (pxg + (k2 << 4)) * 80 + c2;     // 4 px * 20-uint stride
            buf[base]      = pk[k2][0];
            buf[base + 20] = pk[k2][1];
            buf[base + 40] = pk[k2][2];
            buf[base + 60] = pk[k2][3];
        }
        __syncthreads();
        if (i < 7) {                            // ISSUE loads early (hide under MFMA)
#pragma unroll
            for (int k2 = 0; k2 < 2; ++k2) {
                const float* s0 = fb_ + (size_t)(c0 + 32 + (c2 << 1)) * L_ + ((pxg + (k2 << 4)) << 2);
                ra[k2] = *(const float4*)s0;
                rb[k2] = *(const float4*)(s0 + L_);
            }
        }
        short8 A[4], B[4];
#pragma unroll
        for (int t = 0; t < 4; ++t)
            A[t] = *(const short8*)(wb + (size_t)(co0 + (t << 4) + r) * C_ + c0 + (quad << 3));
#pragma unroll
        for (int t = 0; t < 4; ++t)
            B[t] = *(const short8*)((const unsigned short*)buf + (pxl + (t << 4) + r) * 40 + (quad << 3));
#pragma unroll
        for (int pxt = 0; pxt < 4; ++pxt)
#pragma unroll
            for (int cot = 0; cot < 4; ++cot)
                acc[pxt][cot] = __builtin_amdgcn_mfma_f32_16x16x32_bf16(A[cot], B[pxt], acc[pxt][cot], 0, 0, 0);
        if (i < 7) {                            // PACK late, after the MFMA block
#pragma unroll
            for (int k2 = 0; k2 < 2; ++k2) {
                pk[k2][0] = pack2(ra[k2].x, rb[k2].x); pk[k2][1] = pack2(ra[k2].y, rb[k2].y);
                pk[k2][2] = pack2(ra[k2].z, rb[k2].z); pk[k2][3] = pack2(ra[k2].w, rb[k2].w);
            }
        }
    }
#pragma unroll
    for (int pxt = 0; pxt < 4; ++pxt) {
        int px = l0 + pxl + (pxt << 4) + r;
        unsigned short* orow = hb + ((size_t)n * L_ + px) * C_;
#pragma unroll
        for (int cot = 0; cot < 4; ++cot) {
            int cb = co0 + (cot << 4) + (quad << 2);
            float4 bb = *(const float4*)(t1up + n * C_ + cb);
            unsigned int p0 = pack2(fmaxf(acc[pxt][cot][0] + bb.x, 0.f),
                                    fmaxf(acc[pxt][cot][1] + bb.y, 0.f));
            unsigned int p1 = pack2(fmaxf(acc[pxt][cot][2] + bb.z, 0.f),
                                    fmaxf(acc[pxt][cot][3] + bb.w, 0.f));
            *(uint2*)(orow + cb) = make_uint2(p0, p1);
        }
    }
}

// ---------- K10: MFMA gemm2, prefetch-distance-2 LDS-staged B from hb ----------
// out[n,co,l] = relu(hb[n,l,:]·t2wb[co,:] + t2b[co])
__global__ __launch_bounds__(256) void k_gemm2(
    const unsigned short* __restrict__ hb, const unsigned short* __restrict__ wb,
    const float* __restrict__ t2b, float* __restrict__ out)
{
    __shared__ __align__(16) unsigned short lsB[2][128 * 40];   // px stride 40 ushorts (padded)
    int bid = blockIdx.x;                       // 1024
    int co_b = bid & 1, px_b = (bid >> 1) & 31, n = bid >> 6;
    int l0 = px_b << 7;
    int tid = threadIdx.x;
    int wv = tid >> 6, lane = tid & 63;
    int r = lane & 15, quad = lane >> 4;
    int pxl = (wv >> 1) << 6;
    int co0 = (co_b << 7) + ((wv & 1) << 6);
    const unsigned short* hrow = hb + ((size_t)n * L_ + l0) * C_;
    int q = tid & 3, pxs = tid >> 2;            // item 0: px = pxs; item 1: px = pxs+64

    uint4 preA[2], preB[2];
#pragma unroll
    for (int k2 = 0; k2 < 2; ++k2)
        preA[k2] = *(const uint4*)(hrow + (size_t)(pxs + (k2 << 6)) * C_ + (q << 3));
#pragma unroll
    for (int k2 = 0; k2 < 2; ++k2)
        preB[k2] = *(const uint4*)(hrow + (size_t)(pxs + (k2 << 6)) * C_ + 32 + (q << 3));

    f32x4 acc[4][4];
#pragma unroll
    for (int i = 0; i < 4; ++i)
#pragma unroll
        for (int j = 0; j < 4; ++j) acc[i][j] = (f32x4){0.f, 0.f, 0.f, 0.f};

#pragma unroll
    for (int i = 0; i < 8; ++i) {
        int c0 = i << 5;
        unsigned short* buf = lsB[i & 1];
#pragma unroll
        for (int k2 = 0; k2 < 2; ++k2)
            *(uint4*)(buf + (pxs + (k2 << 6)) * 40 + (q << 3)) = preA[k2];
        __syncthreads();
#pragma unroll
        for (int k2 = 0; k2 < 2; ++k2) preA[k2] = preB[k2];
        if (i < 6) {
#pragma unroll
            for (int k2 = 0; k2 < 2; ++k2)
                preB[k2] = *(const uint4*)(hrow + (size_t)(pxs + (k2 << 6)) * C_ + ((i + 2) << 5) + (q << 3));
        }
        short8 A[4], B[4];
#pragma unroll
        for (int t = 0; t < 4; ++t)
            A[t] = *(const short8*)(wb + (size_t)(co0 + (t << 4) + r) * C_ + c0 + (quad << 3));
#pragma unroll
        for (int t = 0; t < 4; ++t)
            B[t] = *(const short8*)(buf + (pxl + (t << 4) + r) * 40 + (quad << 3));
#pragma unroll
        for (int pxt = 0; pxt < 4; ++pxt)
#pragma unroll
            for (int cot = 0; cot < 4; ++cot)
                acc[pxt][cot] = __builtin_amdgcn_mfma_f32_16x16x32_bf16(A[cot], B[pxt], acc[pxt][cot], 0, 0, 0);
    }
#pragma unroll
    for (int pxt = 0; pxt < 4; ++pxt) {
        int px = l0 + pxl + (pxt << 4) + r;
#pragma unroll
        for (int cot = 0; cot < 4; ++cot) {
            int cb = co0 + (cot << 4) + (quad << 2);
            float4 bb = *(const float4*)(t2b + cb);
            out[((size_t)n * C_ + cb + 0) * L_ + px] = fmaxf(acc[pxt][cot][0] + bb.x, 0.f);
            out[((size_t)n * C_ + cb + 1) * L_ + px] = fmaxf(acc[pxt][cot][1] + bb.y, 0.f);
            out[((size_t)n * C_ + cb + 2) * L_ + px] = fmaxf(acc[pxt][cot][2] + bb.z, 0.f);
            out[((size_t)n * C_ + cb + 3) * L_ + px] = fmaxf(acc[pxt][cot][3] + bb.w, 0.f);
        }
    }
}

extern "C" void kernel_launch(void* const* d_in, const int* in_sizes, int n_in,
                              void* d_out, int out_size, void* d_ws, size_t ws_size,
                              hipStream_t stream)
{
    const float* feature = (const float*)d_in[0];
    const float* conv_w  = (const float*)d_in[1];
    const float* conv_b  = (const float*)d_in[2];
    const float* cent    = (const float*)d_in[3];
    const float* upfc_w  = (const float*)d_in[4];
    const float* upfc_b  = (const float*)d_in[5];
    const float* t1w     = (const float*)d_in[6];
    const float* t1b     = (const float*)d_in[7];
    const float* t2w     = (const float*)d_in[8];
    const float* t2b     = (const float*)d_in[9];

    float* ws = (float*)d_ws;                    // 43.3 MB total
    unsigned short* xnb = (unsigned short*)ws;           // 16777216 us (32 MB)
    unsigned short* hb  = xnb;                           // alias: xnb dead after k_conv
    float* rest  = ws + 8388608;
    float* rinv  = rest;                         // 65536
    float* sa    = rinv + 65536;                 // 2097152 (8 MB)
    float* up    = sa + 2097152;                 // 131072
    float* ssum  = up + 131072;                  // 512 (adjacent to up: single memset)
    float* upn   = ssum + 512;                   // 131072
    float* rowss = upn + 131072;                 // 512
    float* upvec = rowss + 512;                  // 4096
    float* t1up  = upvec + 4096;                 // 4096
    unsigned short* wbconv = (unsigned short*)upn;       // alias: upn written later by k_rowfix
    unsigned short* t1wb = (unsigned short*)sa;          // alias: sa dead after k_einsum
    unsigned short* t2wb = t1wb + 65536;
    float* out = (float*)d_out;

    hipMemsetAsync(up, 0, (131072 + 512) * sizeof(float), stream);  // up + ssum
    k_prep     <<<2048, 256, 0, stream>>>(feature, rinv, xnb);
    k_wpack    <<<288,  256, 0, stream>>>(conv_w, wbconv);
    k_conv     <<<1024, 256, 0, stream>>>(xnb, wbconv, conv_b, sa, ssum);
    k_einsum   <<<512,  256, 0, stream>>>(feature, rinv, sa, up);
    k_rowfix   <<<512,  256, 0, stream>>>(up, ssum, cent, upn, rowss);
    k_wpack2   <<<256,  256, 0, stream>>>(t1w, 512, t1wb);
    k_wpack2   <<<256,  256, 0, stream>>>(t2w, 256, t2wb);
    k_fc       <<<256,  256, 0, stream>>>(upn, rowss, upfc_w, upfc_b, upvec);
    k_t1up     <<<256,  256, 0, stream>>>(upvec, t1w, t1b, t1up);
    k_gemm1    <<<1024, 256, 0, stream>>>(feature, t1wb, t1up, hb);
    k_gemm2    <<<1024, 256, 0, stream>>>(hb, t2wb, t2b, out);
}

// Round 2
// 400.020 us; speedup vs baseline: 1.0439x; 1.0439x over previous
//
#include <hip/hip_runtime.h>
#include <cstdint>

#define N_ 16
#define C_ 256
#define H_ 64
#define W_ 64
#define L_ 4096          // H*W
#define K_ 32
#define CL_ (C_*L_)      // 1048576
#define KL_ (K_*L_)      // 131072
#define KC_ (K_*C_)      // 8192

typedef __attribute__((ext_vector_type(8))) short short8;   // 8 bf16 (4 VGPRs)
typedef __attribute__((ext_vector_type(4))) float f32x4;    // MFMA C/D frag

__device__ __forceinline__ unsigned short f2bf(float x) {   // RNE fp32->bf16
    unsigned int u = __float_as_uint(x);
    u += 0x7fffu + ((u >> 16) & 1u);
    return (unsigned short)(u >> 16);
}
__device__ __forceinline__ unsigned int pack2(float a, float b) {
    return (unsigned int)f2bf(a) | ((unsigned int)f2bf(b) << 16);
}

// ---------- K1: fused rinv + xn(bf16) transposed to (n,l,c) ----------
__global__ __launch_bounds__(256) void k_prep(
    const float* __restrict__ f, float* __restrict__ rinv,
    unsigned short* __restrict__ xnb)
{
    __shared__ float tile[256 * 34];            // [c][l], stride 34 (conflict-free)
    __shared__ float ssred[8 * 33];
    __shared__ float rbuf[32];
    int bid = blockIdx.x;
    int n = bid >> 7;
    int l0 = (bid & 127) << 5;
    int tid = threadIdx.x;
    int l = tid & 31, cb = tid >> 5;            // cb 0..7
    const float* fp = f + (size_t)n * CL_ + l0 + l;
    float ss = 0.f;
#pragma unroll
    for (int i = 0; i < 32; ++i) {
        int c = (cb << 5) + i;
        float v = fp[(size_t)c * L_];
        tile[c * 34 + l] = v;
        ss = fmaf(v, v, ss);
    }
    ssred[cb * 33 + l] = ss;
    __syncthreads();
    if (tid < 32) {
        float s = 0.f;
#pragma unroll
        for (int j = 0; j < 8; ++j) s += ssred[j * 33 + tid];
        float ri = 1.0f / fmaxf(sqrtf(s), 1e-12f);
        rinv[n * L_ + l0 + tid] = ri;
        rbuf[tid] = ri;
    }
    __syncthreads();
    float ri = rbuf[l];
    unsigned short* op = xnb + ((size_t)n * L_ + l0 + l) * C_ + (cb << 5);
#pragma unroll
    for (int g = 0; g < 4; ++g) {
        unsigned int pk[4];
#pragma unroll
        for (int d = 0; d < 4; ++d) {
            int c = (cb << 5) + (g << 3) + (d << 1);
            pk[d] = pack2(tile[c * 34 + l] * ri, tile[(c + 1) * 34 + l] * ri);
        }
        *(uint4*)(op + (g << 3)) = make_uint4(pk[0], pk[1], pk[2], pk[3]);
    }
}

// ---------- K2: repack conv weights -> wb[t][k][c] bf16 ----------
__global__ __launch_bounds__(256) void k_wpack(const float* __restrict__ w, unsigned short* __restrict__ wb) {
    int i = blockIdx.x * 256 + threadIdx.x;     // 73728
    int t = i >> 13;
    int k = (i >> 8) & 31;
    int c = i & 255;
    wb[i] = f2bf(w[k * 2304 + c * 9 + t]);
}

// ---------- generic 256x256 weight pack (row stride in floats) ----------
__global__ __launch_bounds__(256) void k_wpack2(const float* __restrict__ w, int stride,
                                                unsigned short* __restrict__ wb) {
    int i = blockIdx.x * 256 + threadIdx.x;     // 65536
    int co = i >> 8, ci = i & 255;
    wb[i] = f2bf(w[(size_t)co * stride + ci]);
}

// ---------- K3: MFMA 3x3 conv + fused softmax + fused ssum ----------
// Key change this round: the per-chunk weight slice (18 KB) is staged into LDS
// (double-buffered) so the compute phase has ZERO global loads. This breaks the
// in-order-vmcnt entanglement where in-loop weight loads had to wait behind the
// HBM prefetch of chunk i+1 (the round-0 latency convoy: 24K cy/chunk, all
// pipes <7%). Compute now waits only on lgkmcnt (ds_read) + MFMA deps.
// LDS 73.7 KB -> 2 blocks/CU (8 waves). Prefetch distance 1 ONLY (distance 2
// spilled to scratch in round 1: WRITE_SIZE 12->220 MB).
// XCD swizzle kept: (n,y)=(bid&15,bid>>4) -> halo re-reads L2-hit (FETCH 56->49 MB).
// W LDS row stride 36 shorts: write + ds_read_b128 both 2-way banked (free).
__global__ __launch_bounds__(256, 2) void k_conv(
    const unsigned short* __restrict__ xnb, const unsigned short* __restrict__ wb,
    const float* __restrict__ bias, float* __restrict__ sa, float* __restrict__ ssum)
{
    __shared__ __align__(16) unsigned short lsB[2][3 * 66 * 40];   // 2 x 15840 B
    __shared__ __align__(16) unsigned short lsW[2][9 * 32 * 36];   // 2 x 20736 B
    __shared__ float sred[4][32];
    int bid = blockIdx.x;
    int n = bid & 15, y = bid >> 4;             // XCD-locality swizzle
    int tid = threadIdx.x;
    int wv = tid >> 6, lane = tid & 63;
    int r = lane & 15, quad = lane >> 4;
    int pxw = (wv << 4) + r;                    // this lane's output x
    const unsigned short* xb = xnb + (size_t)n * CL_;

    // B staging plan: 3 rows x 66 px x 4 quads = 792 uint4 items, 3-4 per thread
    const unsigned short* sptr[4];
    int sidx[4];
    bool svalid[4];
    int scnt = (tid < 24) ? 4 : 3;
#pragma unroll
    for (int k = 0; k < 4; ++k) {
        int j = tid + (k << 8);
        int row = j / 264; if (row > 2) row = 2;
        int rem = j - row * 264;
        int px = rem >> 2, q = rem & 3;
        int yy = y + row - 1, xx = px - 1;
        bool ok = ((unsigned)yy < 64u) && ((unsigned)xx < 64u);
        int yc = ok ? yy : 0, xc = ok ? xx : 0;
        sptr[k] = xb + (((size_t)(yc << 6) + xc) << 8) + (q << 3);
        svalid[k] = ok;
        sidx[k] = (row * 66 + px) * 40 + (q << 3);
    }
    // W staging plan: 9 taps x 32 k x 4 g = 1152 uint4 items; 4 per thread + 1 for tid<128
    const unsigned short* wptr[5];
    int widx[5];
#pragma unroll
    for (int s = 0; s < 5; ++s) {
        int j = tid + (s << 8);
        int t = j >> 7, k = (j >> 2) & 31, g = j & 3;
        wptr[s] = wb + t * 8192 + k * 256 + (g << 3);
        widx[s] = (t * 32 + k) * 36 + (g << 3);
    }
    bool w5 = (tid < 128);

    const uint4 z4 = make_uint4(0, 0, 0, 0);
    uint4 preB[4];
    uint4 preW[5];
#pragma unroll
    for (int k = 0; k < 4; ++k)
        preB[k] = (k < scnt && svalid[k]) ? *(const uint4*)sptr[k] : z4;   // chunk 0
#pragma unroll
    for (int s = 0; s < 4; ++s) preW[s] = *(const uint4*)wptr[s];
    preW[4] = w5 ? *(const uint4*)wptr[4] : z4;

    f32x4 acc0 = (f32x4){0.f, 0.f, 0.f, 0.f};
    f32x4 acc1 = (f32x4){0.f, 0.f, 0.f, 0.f};
    for (int i = 0; i < 8; ++i) {
        int c0 = i << 5;
        unsigned short* bufB = lsB[i & 1];
        unsigned short* bufW = lsW[i & 1];
#pragma unroll
        for (int k = 0; k < 4; ++k)
            if (k < scnt) *(uint4*)(bufB + sidx[k]) = preB[k];
#pragma unroll
        for (int s = 0; s < 4; ++s) *(uint4*)(bufW + widx[s]) = preW[s];
        if (w5) *(uint4*)(bufW + widx[4]) = preW[4];
        __syncthreads();                        // single barrier/chunk (dbuf proof holds for B and W)
        if (i < 7) {
            int c1 = c0 + 32;
#pragma unroll
            for (int k = 0; k < 4; ++k)
                preB[k] = (k < scnt && svalid[k]) ? *(const uint4*)(sptr[k] + c1) : z4;
#pragma unroll
            for (int s = 0; s < 4; ++s) preW[s] = *(const uint4*)(wptr[s] + c1);
            preW[4] = w5 ? *(const uint4*)(wptr[4] + c1) : z4;
        }
#pragma unroll
        for (int t = 0; t < 9; ++t) {
            int dy = t / 3, dx = t % 3;
            short8 B  = *(const short8*)(bufB + (dy * 66 + pxw + dx) * 40 + (quad << 3));
            short8 A0 = *(const short8*)(bufW + (t * 32 + r) * 36 + (quad << 3));
            short8 A1 = *(const short8*)(bufW + (t * 32 + 16 + r) * 36 + (quad << 3));
            acc0 = __builtin_amdgcn_mfma_f32_16x16x32_bf16(A0, B, acc0, 0, 0, 0);
            acc1 = __builtin_amdgcn_mfma_f32_16x16x32_bf16(A1, B, acc1, 0, 0, 0);
        }
    }
    // bias + softmax over k (32 values per px: 4 quads x 8 regs)
    float4 b0 = *(const float4*)(bias + (quad << 2));
    float4 b1 = *(const float4*)(bias + 16 + (quad << 2));
    float v[8];
    v[0] = acc0[0] + b0.x; v[1] = acc0[1] + b0.y; v[2] = acc0[2] + b0.z; v[3] = acc0[3] + b0.w;
    v[4] = acc1[0] + b1.x; v[5] = acc1[1] + b1.y; v[6] = acc1[2] + b1.z; v[7] = acc1[3] + b1.w;
    float mx = v[0];
#pragma unroll
    for (int j = 1; j < 8; ++j) mx = fmaxf(mx, v[j]);
    mx = fmaxf(mx, __shfl_xor(mx, 16));
    mx = fmaxf(mx, __shfl_xor(mx, 32));
    float s = 0.f;
#pragma unroll
    for (int j = 0; j < 8; ++j) { v[j] = __expf(v[j] - mx); s += v[j]; }
    s += __shfl_xor(s, 16);
    s += __shfl_xor(s, 32);
    float rs = 1.0f / s;
    float sv8[8];
#pragma unroll
    for (int j = 0; j < 8; ++j) sv8[j] = v[j] * rs;
    int l = (y << 6) + pxw;
    float* sp = sa + (size_t)n * KL_ + l;
#pragma unroll
    for (int j = 0; j < 4; ++j) {
        sp[(size_t)((quad << 2) + j) * L_] = sv8[j];
        sp[(size_t)(16 + (quad << 2) + j) * L_] = sv8[4 + j];
    }
    // fused ssum: reduce over the wave's 16 px (lane bits 0-3), combine waves in LDS
#pragma unroll
    for (int j = 0; j < 8; ++j) {
        float a = sv8[j];
        a += __shfl_xor(a, 1); a += __shfl_xor(a, 2);
        a += __shfl_xor(a, 4); a += __shfl_xor(a, 8);
        sv8[j] = a;
    }
    if (r == 0) {
#pragma unroll
        for (int j = 0; j < 4; ++j) {
            sred[wv][(quad << 2) + j] = sv8[j];
            sred[wv][16 + (quad << 2) + j] = sv8[4 + j];
        }
    }
    __syncthreads();
    if (tid < 32) {
        float t = sred[0][tid] + sred[1][tid] + sred[2][tid] + sred[3][tid];
        atomicAdd(ssum + n * K_ + tid, t);
    }
}

// ---------- K5: up[n,k,c] += sum_l sa[n,k,l] * xn[n,c,l] ----------
__global__ __launch_bounds__(256) void k_einsum(
    const float* __restrict__ f, const float* __restrict__ rinv,
    const float* __restrict__ sa, float* __restrict__ up)
{
    __shared__ float xn_s[C_ * 33];
    __shared__ float sa_s[K_ * 32];
    int bid = blockIdx.x;                       // 512
    int n = bid >> 5;
    int l0 = (bid & 31) << 7;
    int tid = threadIdx.x;
    int kq = tid >> 5, cq = tid & 31;
    float acc[4][8];
#pragma unroll
    for (int i = 0; i < 4; ++i)
#pragma unroll
        for (int j = 0; j < 8; ++j) acc[i][j] = 0.f;

    for (int ch = 0; ch < 4; ++ch) {
        int lc = l0 + (ch << 5);
        __syncthreads();
        {
            int crow = tid >> 3, lq = (tid & 7) << 2;
#pragma unroll
            for (int p = 0; p < 8; ++p) {
                int c = (p << 5) + crow;
                float4 f4 = *(const float4*)(f + (size_t)n * CL_ + (size_t)c * L_ + lc + lq);
                float4 r4 = *(const float4*)(rinv + n * L_ + lc + lq);
                float* d = xn_s + c * 33 + lq;
                d[0] = f4.x * r4.x; d[1] = f4.y * r4.y; d[2] = f4.z * r4.z; d[3] = f4.w * r4.w;
            }
        }
        {
            int k = tid >> 3, lq = (tid & 7) << 2;
            float4 a4 = *(const float4*)(sa + (size_t)n * KL_ + (size_t)k * L_ + lc + lq);
            *(float4*)(sa_s + (k << 5) + lq) = a4;
        }
        __syncthreads();
#pragma unroll 4
        for (int l = 0; l < 32; ++l) {
            float sv[4], xv[8];
#pragma unroll
            for (int i = 0; i < 4; ++i) sv[i] = sa_s[((kq << 2) + i) * 32 + l];
#pragma unroll
            for (int j = 0; j < 8; ++j) xv[j] = xn_s[(cq + (j << 5)) * 33 + l];
#pragma unroll
            for (int i = 0; i < 4; ++i)
#pragma unroll
                for (int j = 0; j < 8; ++j) acc[i][j] = fmaf(sv[i], xv[j], acc[i][j]);
        }
    }
    float* upp = up + (size_t)n * KC_;
#pragma unroll
    for (int i = 0; i < 4; ++i)
#pragma unroll
        for (int j = 0; j < 8; ++j)
            atomicAdd(upp + ((kq << 2) + i) * C_ + cq + (j << 5), acc[i][j]);
}

// ---------- K6: subtract centroid term, l2norm rows, record row sumsq ----------
__global__ __launch_bounds__(256) void k_rowfix(
    const float* __restrict__ up, const float* __restrict__ ssum,
    const float* __restrict__ cent, float* __restrict__ upn, float* __restrict__ rowss)
{
    __shared__ float red[256];
    int bid = blockIdx.x;                       // n*K + k
    int k = bid & 31;
    float sv = ssum[bid];
    float v = up[(size_t)bid * C_ + threadIdx.x] - sv * cent[k * C_ + threadIdx.x];
    red[threadIdx.x] = v * v; __syncthreads();
    for (int st = 128; st > 0; st >>= 1) {
        if (threadIdx.x < st) red[threadIdx.x] += red[threadIdx.x + st];
        __syncthreads();
    }
    float ss = red[0];
    float ri = 1.0f / fmaxf(sqrtf(ss), 1e-12f);
    upn[(size_t)bid * C_ + threadIdx.x] = v * ri;
    if (threadIdx.x == 0) rowss[bid] = ss * ri * ri;
}

// ---------- K7: global l2norm + FC, one block per output channel c ----------
__global__ __launch_bounds__(256) void k_fc(
    const float* __restrict__ upn, const float* __restrict__ rowss,
    const float* __restrict__ w, const float* __restrict__ b,
    float* __restrict__ upvec)
{
    __shared__ float rnb[16];
    __shared__ float red[16][5];
    int c = blockIdx.x;                         // 256
    int tid = threadIdx.x;
    int wv = tid >> 6, lane = tid & 63;
    if (tid < 16) {
        float ts = 0.f;
#pragma unroll
        for (int k = 0; k < K_; ++k) ts += rowss[(tid << 5) + k];
        rnb[tid] = 1.0f / fmaxf(sqrtf(ts), 1e-12f);
    }
    float acc[16];
#pragma unroll
    for (int n = 0; n < 16; ++n) acc[n] = 0.f;
    const float* wr = w + (size_t)c * KC_;
#pragma unroll
    for (int g = 0; g < 8; ++g) {
        int kc = (g << 10) + (tid << 2);
        float4 w4 = *(const float4*)(wr + kc);
#pragma unroll
        for (int n = 0; n < 16; ++n) {
            float4 u4 = *(const float4*)(upn + n * KC_ + kc);
            acc[n] += w4.x * u4.x + w4.y * u4.y + w4.z * u4.z + w4.w * u4.w;
        }
    }
#pragma unroll
    for (int n = 0; n < 16; ++n) {
        float a = acc[n];
#pragma unroll
        for (int s = 1; s < 64; s <<= 1) a += __shfl_xor(a, s);
        if (lane == 0) red[n][wv] = a;
    }
    __syncthreads();
    if (tid < 16) {
        float v = red[tid][0] + red[tid][1] + red[tid][2] + red[tid][3];
        upvec[tid * C_ + c] = v * rnb[tid] + b[c];
    }
}

// ---------- K8: t1up[n,co] = t1_w[co,256:512] . upvec[n,:] + t1_b[co] ----------
__global__ __launch_bounds__(256) void k_t1up(
    const float* __restrict__ upvec, const float* __restrict__ t1w,
    const float* __restrict__ t1b, float* __restrict__ t1up)
{
    __shared__ float wld[256];
    int co = blockIdx.x;                        // 256
    int tid = threadIdx.x;
    wld[tid] = t1w[(size_t)co * 512 + 256 + tid];
    __syncthreads();
    int n = tid >> 4, s = tid & 15;
    float a = 0.f;
#pragma unroll
    for (int i = 0; i < 16; ++i)
        a += wld[s + (i << 4)] * upvec[n * C_ + s + (i << 4)];
#pragma unroll
    for (int st = 1; st < 16; st <<= 1) a += __shfl_xor(a, st);
    if (s == 0) t1up[n * C_ + co] = a + t1b[co];
}

// ---------- K9: MFMA gemm1, pipelined LDS-staged B from fp32 feature ----------
// hb[n,l,co] = bf16(relu(f[n,:,l]·t1wb[co,:] + t1up[n,co]))
__global__ __launch_bounds__(256) void k_gemm1(
    const float* __restrict__ f, const unsigned short* __restrict__ wb,
    const float* __restrict__ t1up, unsigned short* __restrict__ hb)
{
    __shared__ __align__(16) unsigned int lsB[2][128 * 20];     // px stride 20 uints (padded)
    int bid = blockIdx.x;                       // 1024 = n(16) x px_b(32) x co_b(2)
    int co_b = bid & 1, px_b = (bid >> 1) & 31, n = bid >> 6;
    int l0 = px_b << 7;
    int tid = threadIdx.x;
    int wv = tid >> 6, lane = tid & 63;
    int r = lane & 15, quad = lane >> 4;
    int pxl = (wv >> 1) << 6;                   // block-local px base for wave
    int co0 = (co_b << 7) + ((wv & 1) << 6);
    const float* fb_ = f + (size_t)n * CL_ + l0;
    int c2 = tid & 15, pxg = tid >> 4;          // item 0; item 1 = +256 -> pxg+16

    unsigned int pk[2][4];
#pragma unroll
    for (int k2 = 0; k2 < 2; ++k2) {
        const float* s0 = fb_ + (size_t)(c2 << 1) * L_ + ((pxg + (k2 << 4)) << 2);
        float4 a = *(const float4*)s0;
        float4 b = *(const float4*)(s0 + L_);
        pk[k2][0] = pack2(a.x, b.x); pk[k2][1] = pack2(a.y, b.y);
        pk[k2][2] = pack2(a.z, b.z); pk[k2][3] = pack2(a.w, b.w);
    }
    f32x4 acc[4][4];
#pragma unroll
    for (int i = 0; i < 4; ++i)
#pragma unroll
        for (int j = 0; j < 4; ++j) acc[i][j] = (f32x4){0.f, 0.f, 0.f, 0.f};

    for (int i = 0; i < 8; ++i) {
        int c0 = i << 5;
        unsigned int* buf = lsB[i & 1];
#pragma unroll
        for (int k2 = 0; k2 < 2; ++k2) {
            int base = (pxg + (k2 << 4)) * 80 + c2;     // 4 px * 20-uint stride
            buf[base]      = pk[k2][0];
            buf[base + 20] = pk[k2][1];
            buf[base + 40] = pk[k2][2];
            buf[base + 60] = pk[k2][3];
        }
        __syncthreads();
        if (i < 7) {
#pragma unroll
            for (int k2 = 0; k2 < 2; ++k2) {
                const float* s0 = fb_ + (size_t)(c0 + 32 + (c2 << 1)) * L_ + ((pxg + (k2 << 4)) << 2);
                float4 a = *(const float4*)s0;
                float4 b = *(const float4*)(s0 + L_);
                pk[k2][0] = pack2(a.x, b.x); pk[k2][1] = pack2(a.y, b.y);
                pk[k2][2] = pack2(a.z, b.z); pk[k2][3] = pack2(a.w, b.w);
            }
        }
        short8 A[4], B[4];
#pragma unroll
        for (int t = 0; t < 4; ++t)
            A[t] = *(const short8*)(wb + (size_t)(co0 + (t << 4) + r) * C_ + c0 + (quad << 3));
#pragma unroll
        for (int t = 0; t < 4; ++t)
            B[t] = *(const short8*)((const unsigned short*)buf + (pxl + (t << 4) + r) * 40 + (quad << 3));
#pragma unroll
        for (int pxt = 0; pxt < 4; ++pxt)
#pragma unroll
            for (int cot = 0; cot < 4; ++cot)
                acc[pxt][cot] = __builtin_amdgcn_mfma_f32_16x16x32_bf16(A[cot], B[pxt], acc[pxt][cot], 0, 0, 0);
    }
#pragma unroll
    for (int pxt = 0; pxt < 4; ++pxt) {
        int px = l0 + pxl + (pxt << 4) + r;
        unsigned short* orow = hb + ((size_t)n * L_ + px) * C_;
#pragma unroll
        for (int cot = 0; cot < 4; ++cot) {
            int cb = co0 + (cot << 4) + (quad << 2);
            float4 bb = *(const float4*)(t1up + n * C_ + cb);
            unsigned int p0 = pack2(fmaxf(acc[pxt][cot][0] + bb.x, 0.f),
                                    fmaxf(acc[pxt][cot][1] + bb.y, 0.f));
            unsigned int p1 = pack2(fmaxf(acc[pxt][cot][2] + bb.z, 0.f),
                                    fmaxf(acc[pxt][cot][3] + bb.w, 0.f));
            *(uint2*)(orow + cb) = make_uint2(p0, p1);
        }
    }
}

// ---------- K10: MFMA gemm2, pipelined LDS-staged B from hb ----------
// out[n,co,l] = relu(hb[n,l,:]·t2wb[co,:] + t2b[co])
__global__ __launch_bounds__(256) void k_gemm2(
    const unsigned short* __restrict__ hb, const unsigned short* __restrict__ wb,
    const float* __restrict__ t2b, float* __restrict__ out)
{
    __shared__ __align__(16) unsigned short lsB[2][128 * 40];   // px stride 40 ushorts (padded)
    int bid = blockIdx.x;                       // 1024
    int co_b = bid & 1, px_b = (bid >> 1) & 31, n = bid >> 6;
    int l0 = px_b << 7;
    int tid = threadIdx.x;
    int wv = tid >> 6, lane = tid & 63;
    int r = lane & 15, quad = lane >> 4;
    int pxl = (wv >> 1) << 6;
    int co0 = (co_b << 7) + ((wv & 1) << 6);
    const unsigned short* hrow = hb + ((size_t)n * L_ + l0) * C_;
    int q = tid & 3, pxs = tid >> 2;            // item 0: px = pxs; item 1: px = pxs+64

    uint4 pre[2];
#pragma unroll
    for (int k2 = 0; k2 < 2; ++k2)
        pre[k2] = *(const uint4*)(hrow + (size_t)(pxs + (k2 << 6)) * C_ + (q << 3));

    f32x4 acc[4][4];
#pragma unroll
    for (int i = 0; i < 4; ++i)
#pragma unroll
        for (int j = 0; j < 4; ++j) acc[i][j] = (f32x4){0.f, 0.f, 0.f, 0.f};

    for (int i = 0; i < 8; ++i) {
        int c0 = i << 5;
        unsigned short* buf = lsB[i & 1];
#pragma unroll
        for (int k2 = 0; k2 < 2; ++k2)
            *(uint4*)(buf + (pxs + (k2 << 6)) * 40 + (q << 3)) = pre[k2];
        __syncthreads();
        if (i < 7) {
#pragma unroll
            for (int k2 = 0; k2 < 2; ++k2)
                pre[k2] = *(const uint4*)(hrow + (size_t)(pxs + (k2 << 6)) * C_ + c0 + 32 + (q << 3));
        }
        short8 A[4], B[4];
#pragma unroll
        for (int t = 0; t < 4; ++t)
            A[t] = *(const short8*)(wb + (size_t)(co0 + (t << 4) + r) * C_ + c0 + (quad << 3));
#pragma unroll
        for (int t = 0; t < 4; ++t)
            B[t] = *(const short8*)(buf + (pxl + (t << 4) + r) * 40 + (quad << 3));
#pragma unroll
        for (int pxt = 0; pxt < 4; ++pxt)
#pragma unroll
            for (int cot = 0; cot < 4; ++cot)
                acc[pxt][cot] = __builtin_amdgcn_mfma_f32_16x16x32_bf16(A[cot], B[pxt], acc[pxt][cot], 0, 0, 0);
    }
#pragma unroll
    for (int pxt = 0; pxt < 4; ++pxt) {
        int px = l0 + pxl + (pxt << 4) + r;
#pragma unroll
        for (int cot = 0; cot < 4; ++cot) {
            int cb = co0 + (cot << 4) + (quad << 2);
            float4 bb = *(const float4*)(t2b + cb);
            out[((size_t)n * C_ + cb + 0) * L_ + px] = fmaxf(acc[pxt][cot][0] + bb.x, 0.f);
            out[((size_t)n * C_ + cb + 1) * L_ + px] = fmaxf(acc[pxt][cot][1] + bb.y, 0.f);
            out[((size_t)n * C_ + cb + 2) * L_ + px] = fmaxf(acc[pxt][cot][2] + bb.z, 0.f);
            out[((size_t)n * C_ + cb + 3) * L_ + px] = fmaxf(acc[pxt][cot][3] + bb.w, 0.f);
        }
    }
}

extern "C" void kernel_launch(void* const* d_in, const int* in_sizes, int n_in,
                              void* d_out, int out_size, void* d_ws, size_t ws_size,
                              hipStream_t stream)
{
    const float* feature = (const float*)d_in[0];
    const float* conv_w  = (const float*)d_in[1];
    const float* conv_b  = (const float*)d_in[2];
    const float* cent    = (const float*)d_in[3];
    const float* upfc_w  = (const float*)d_in[4];
    const float* upfc_b  = (const float*)d_in[5];
    const float* t1w     = (const float*)d_in[6];
    const float* t1b     = (const float*)d_in[7];
    const float* t2w     = (const float*)d_in[8];
    const float* t2b     = (const float*)d_in[9];

    float* ws = (float*)d_ws;                    // 43.3 MB total
    unsigned short* xnb = (unsigned short*)ws;           // 16777216 us (32 MB)
    unsigned short* hb  = xnb;                           // alias: xnb dead after k_conv
    float* rest  = ws + 8388608;
    float* rinv  = rest;                         // 65536
    float* sa    = rinv + 65536;                 // 2097152 (8 MB)
    float* up    = sa + 2097152;                 // 131072
    float* ssum  = up + 131072;                  // 512 (adjacent to up: single memset)
    float* upn   = ssum + 512;                   // 131072
    float* rowss = upn + 131072;                 // 512
    float* upvec = rowss + 512;                  // 4096
    float* t1up  = upvec + 4096;                 // 4096
    unsigned short* wbconv = (unsigned short*)upn;       // alias: upn written later by k_rowfix
    unsigned short* t1wb = (unsigned short*)sa;          // alias: sa dead after k_einsum
    unsigned short* t2wb = t1wb + 65536;
    float* out = (float*)d_out;

    hipMemsetAsync(up, 0, (131072 + 512) * sizeof(float), stream);  // up + ssum
    k_prep     <<<2048, 256, 0, stream>>>(feature, rinv, xnb);
    k_wpack    <<<288,  256, 0, stream>>>(conv_w, wbconv);
    k_conv     <<<1024, 256, 0, stream>>>(xnb, wbconv, conv_b, sa, ssum);
    k_einsum   <<<512,  256, 0, stream>>>(feature, rinv, sa, up);
    k_rowfix   <<<512,  256, 0, stream>>>(up, ssum, cent, upn, rowss);
    k_wpack2   <<<256,  256, 0, stream>>>(t1w, 512, t1wb);
    k_wpack2   <<<256,  256, 0, stream>>>(t2w, 256, t2wb);
    k_fc       <<<256,  256, 0, stream>>>(upn, rowss, upfc_w, upfc_b, upvec);
    k_t1up     <<<256,  256, 0, stream>>>(upvec, t1w, t1b, t1up);
    k_gemm1    <<<1024, 256, 0, stream>>>(feature, t1wb, t1up, hb);
    k_gemm2    <<<1024, 256, 0, stream>>>(hb, t2wb, t2b, out);
}

// Round 3
// 352.082 us; speedup vs baseline: 1.1861x; 1.1362x over previous
//
#include <hip/hip_runtime.h>
#include <cstdint>

#define N_ 16
#define C_ 256
#define H_ 64
#define W_ 64
#define L_ 4096          // H*W
#define K_ 32
#define CL_ (C_*L_)      // 1048576
#define KL_ (K_*L_)      // 131072
#define KC_ (K_*C_)      // 8192

typedef __attribute__((ext_vector_type(8))) short short8;   // 8 bf16 (4 VGPRs)
typedef __attribute__((ext_vector_type(4))) float f32x4;    // MFMA C/D frag

__device__ __forceinline__ unsigned short f2bf(float x) {   // RNE fp32->bf16
    unsigned int u = __float_as_uint(x);
    u += 0x7fffu + ((u >> 16) & 1u);
    return (unsigned short)(u >> 16);
}
__device__ __forceinline__ unsigned int pack2(float a, float b) {
    return (unsigned int)f2bf(a) | ((unsigned int)f2bf(b) << 16);
}

// ---------- K1: fused rinv + xn(bf16) transposed to (n,l,c) ----------
__global__ __launch_bounds__(256) void k_prep(
    const float* __restrict__ f, float* __restrict__ rinv,
    unsigned short* __restrict__ xnb)
{
    __shared__ float tile[256 * 34];            // [c][l], stride 34 (conflict-free)
    __shared__ float ssred[8 * 33];
    __shared__ float rbuf[32];
    int bid = blockIdx.x;
    int n = bid >> 7;
    int l0 = (bid & 127) << 5;
    int tid = threadIdx.x;
    int l = tid & 31, cb = tid >> 5;            // cb 0..7
    const float* fp = f + (size_t)n * CL_ + l0 + l;
    float ss = 0.f;
#pragma unroll
    for (int i = 0; i < 32; ++i) {
        int c = (cb << 5) + i;
        float v = fp[(size_t)c * L_];
        tile[c * 34 + l] = v;
        ss = fmaf(v, v, ss);
    }
    ssred[cb * 33 + l] = ss;
    __syncthreads();
    if (tid < 32) {
        float s = 0.f;
#pragma unroll
        for (int j = 0; j < 8; ++j) s += ssred[j * 33 + tid];
        float ri = 1.0f / fmaxf(sqrtf(s), 1e-12f);
        rinv[n * L_ + l0 + tid] = ri;
        rbuf[tid] = ri;
    }
    __syncthreads();
    float ri = rbuf[l];
    unsigned short* op = xnb + ((size_t)n * L_ + l0 + l) * C_ + (cb << 5);
#pragma unroll
    for (int g = 0; g < 4; ++g) {
        unsigned int pk[4];
#pragma unroll
        for (int d = 0; d < 4; ++d) {
            int c = (cb << 5) + (g << 3) + (d << 1);
            pk[d] = pack2(tile[c * 34 + l] * ri, tile[(c + 1) * 34 + l] * ri);
        }
        *(uint4*)(op + (g << 3)) = make_uint4(pk[0], pk[1], pk[2], pk[3]);
    }
}

// ---------- K2: repack conv weights -> wb[t][k][c] bf16 ----------
__global__ __launch_bounds__(256) void k_wpack(const float* __restrict__ w, unsigned short* __restrict__ wb) {
    int i = blockIdx.x * 256 + threadIdx.x;     // 73728
    int t = i >> 13;
    int k = (i >> 8) & 31;
    int c = i & 255;
    wb[i] = f2bf(w[k * 2304 + c * 9 + t]);
}

// ---------- generic 256x256 weight pack (row stride in floats) ----------
__global__ __launch_bounds__(256) void k_wpack2(const float* __restrict__ w, int stride,
                                                unsigned short* __restrict__ wb) {
    int i = blockIdx.x * 256 + threadIdx.x;     // 65536
    int co = i >> 8, ci = i & 255;
    wb[i] = f2bf(w[(size_t)co * stride + ci]);
}

// ---------- K3: double-buffered, software-pipelined MFMA 3x3 conv + fused softmax ----------
// EXACT round-0 body (proven: 79 us, WRITE_SIZE 12 MB, VGPR 52) with ONE change:
// XCD-locality swizzle (n,y) = (bid&15, bid>>4). bid%8 == n%8 -> each XCD hosts
// exactly 2 images (4 MB xnb = L2 size), so the 3x halo re-reads and the staged
// B-prefetch hit L2 instead of HBM (r1/r2 evidence: FETCH 56 -> 28-49 MB).
// NO weight-LDS staging, NO prefetch-distance-2, NO fused ssum: both r1 and r2
// bundled large cross-barrier register staging and paid ~240 MB of spill-evict
// write traffic (WRITE_SIZE 220/253 MB, +50 us). One variable this round.
__global__ __launch_bounds__(256, 4) void k_conv(
    const unsigned short* __restrict__ xnb, const unsigned short* __restrict__ wb,
    const float* __restrict__ bias, float* __restrict__ sa)
{
    __shared__ __align__(16) unsigned short lsB[2][3 * 66 * 40];   // 2 x 15840 B
    int bid = blockIdx.x;
    int n = bid & 15, y = bid >> 4;             // XCD-locality swizzle (only change vs r0)
    int tid = threadIdx.x;
    int wv = tid >> 6, lane = tid & 63;
    int r = lane & 15, quad = lane >> 4;
    int pxw = (wv << 4) + r;                    // this lane's output x
    const unsigned short* xb = xnb + (size_t)n * CL_;

    // staging plan: 3 rows x 66 px x 4 quads = 792 uint4 items, 3-4 per thread
    const unsigned short* sptr[4];
    int sidx[4];
    bool svalid[4];
    int scnt = (tid < 24) ? 4 : 3;
#pragma unroll
    for (int k = 0; k < 4; ++k) {
        int j = tid + (k << 8);
        int row = j / 264; if (row > 2) row = 2;
        int rem = j - row * 264;
        int px = rem >> 2, q = rem & 3;
        int yy = y + row - 1, xx = px - 1;
        bool ok = ((unsigned)yy < 64u) && ((unsigned)xx < 64u);
        int yc = ok ? yy : 0, xc = ok ? xx : 0;
        sptr[k] = xb + (((size_t)(yc << 6) + xc) << 8) + (q << 3);
        svalid[k] = ok;
        sidx[k] = (row * 66 + px) * 40 + (q << 3);
    }
    const uint4 z4 = make_uint4(0, 0, 0, 0);
    uint4 pre[4];
#pragma unroll
    for (int k = 0; k < 4; ++k)
        pre[k] = (k < scnt && svalid[k]) ? *(const uint4*)sptr[k] : z4;

    f32x4 acc0 = (f32x4){0.f, 0.f, 0.f, 0.f};
    f32x4 acc1 = (f32x4){0.f, 0.f, 0.f, 0.f};
    for (int i = 0; i < 8; ++i) {
        int c0 = i << 5;
        unsigned short* buf = lsB[i & 1];
#pragma unroll
        for (int k = 0; k < 4; ++k)
            if (k < scnt) *(uint4*)(buf + sidx[k]) = pre[k];
        __syncthreads();                        // single barrier/chunk (see proof in journal)
        if (i < 7) {
#pragma unroll
            for (int k = 0; k < 4; ++k)
                pre[k] = (k < scnt && svalid[k]) ? *(const uint4*)(sptr[k] + c0 + 32) : z4;
        }
        const unsigned short* wchunk = wb + c0 + (quad << 3);
#pragma unroll
        for (int t = 0; t < 9; ++t) {
            int dy = t / 3, dx = t % 3;
            short8 B  = *(const short8*)(buf + (dy * 66 + pxw + dx) * 40 + (quad << 3));
            short8 A0 = *(const short8*)(wchunk + t * 8192 + r * 256);
            short8 A1 = *(const short8*)(wchunk + t * 8192 + (16 + r) * 256);
            acc0 = __builtin_amdgcn_mfma_f32_16x16x32_bf16(A0, B, acc0, 0, 0, 0);
            acc1 = __builtin_amdgcn_mfma_f32_16x16x32_bf16(A1, B, acc1, 0, 0, 0);
        }
    }
    // bias + softmax over k (32 values per px: 4 quads x 8 regs)
    float4 b0 = *(const float4*)(bias + (quad << 2));
    float4 b1 = *(const float4*)(bias + 16 + (quad << 2));
    float v[8];
    v[0] = acc0[0] + b0.x; v[1] = acc0[1] + b0.y; v[2] = acc0[2] + b0.z; v[3] = acc0[3] + b0.w;
    v[4] = acc1[0] + b1.x; v[5] = acc1[1] + b1.y; v[6] = acc1[2] + b1.z; v[7] = acc1[3] + b1.w;
    float mx = v[0];
#pragma unroll
    for (int j = 1; j < 8; ++j) mx = fmaxf(mx, v[j]);
    mx = fmaxf(mx, __shfl_xor(mx, 16));
    mx = fmaxf(mx, __shfl_xor(mx, 32));
    float s = 0.f;
#pragma unroll
    for (int j = 0; j < 8; ++j) { v[j] = __expf(v[j] - mx); s += v[j]; }
    s += __shfl_xor(s, 16);
    s += __shfl_xor(s, 32);
    float rs = 1.0f / s;
    int l = (y << 6) + pxw;
    float* sp = sa + (size_t)n * KL_ + l;
#pragma unroll
    for (int j = 0; j < 4; ++j) {
        sp[(size_t)((quad << 2) + j) * L_] = v[j] * rs;
        sp[(size_t)(16 + (quad << 2) + j) * L_] = v[4 + j] * rs;
    }
}

// ---------- K4: ssum[n,k] = sum_l sa[n,k,l] ----------
__global__ __launch_bounds__(256) void k_ssum(const float* __restrict__ sa, float* __restrict__ ssum) {
    __shared__ float red[256];
    int bid = blockIdx.x;                       // n*K + k
    const float* sp = sa + (size_t)bid * L_;
    float s = 0.f;
    for (int m = 0; m < 16; ++m) s += sp[threadIdx.x + (m << 8)];
    red[threadIdx.x] = s; __syncthreads();
    for (int st = 128; st > 0; st >>= 1) {
        if (threadIdx.x < st) red[threadIdx.x] += red[threadIdx.x + st];
        __syncthreads();
    }
    if (threadIdx.x == 0) ssum[bid] = red[0];
}

// ---------- K5: up[n,k,c] += sum_l sa[n,k,l] * xn[n,c,l] ----------
__global__ __launch_bounds__(256) void k_einsum(
    const float* __restrict__ f, const float* __restrict__ rinv,
    const float* __restrict__ sa, float* __restrict__ up)
{
    __shared__ float xn_s[C_ * 33];
    __shared__ float sa_s[K_ * 32];
    int bid = blockIdx.x;                       // 512
    int n = bid >> 5;
    int l0 = (bid & 31) << 7;
    int tid = threadIdx.x;
    int kq = tid >> 5, cq = tid & 31;
    float acc[4][8];
#pragma unroll
    for (int i = 0; i < 4; ++i)
#pragma unroll
        for (int j = 0; j < 8; ++j) acc[i][j] = 0.f;

    for (int ch = 0; ch < 4; ++ch) {
        int lc = l0 + (ch << 5);
        __syncthreads();
        {
            int crow = tid >> 3, lq = (tid & 7) << 2;
#pragma unroll
            for (int p = 0; p < 8; ++p) {
                int c = (p << 5) + crow;
                float4 f4 = *(const float4*)(f + (size_t)n * CL_ + (size_t)c * L_ + lc + lq);
                float4 r4 = *(const float4*)(rinv + n * L_ + lc + lq);
                float* d = xn_s + c * 33 + lq;
                d[0] = f4.x * r4.x; d[1] = f4.y * r4.y; d[2] = f4.z * r4.z; d[3] = f4.w * r4.w;
            }
        }
        {
            int k = tid >> 3, lq = (tid & 7) << 2;
            float4 a4 = *(const float4*)(sa + (size_t)n * KL_ + (size_t)k * L_ + lc + lq);
            *(float4*)(sa_s + (k << 5) + lq) = a4;
        }
        __syncthreads();
#pragma unroll 4
        for (int l = 0; l < 32; ++l) {
            float sv[4], xv[8];
#pragma unroll
            for (int i = 0; i < 4; ++i) sv[i] = sa_s[((kq << 2) + i) * 32 + l];
#pragma unroll
            for (int j = 0; j < 8; ++j) xv[j] = xn_s[(cq + (j << 5)) * 33 + l];
#pragma unroll
            for (int i = 0; i < 4; ++i)
#pragma unroll
                for (int j = 0; j < 8; ++j) acc[i][j] = fmaf(sv[i], xv[j], acc[i][j]);
        }
    }
    float* upp = up + (size_t)n * KC_;
#pragma unroll
    for (int i = 0; i < 4; ++i)
#pragma unroll
        for (int j = 0; j < 8; ++j)
            atomicAdd(upp + ((kq << 2) + i) * C_ + cq + (j << 5), acc[i][j]);
}

// ---------- K6: subtract centroid term, l2norm rows, record row sumsq ----------
__global__ __launch_bounds__(256) void k_rowfix(
    const float* __restrict__ up, const float* __restrict__ ssum,
    const float* __restrict__ cent, float* __restrict__ upn, float* __restrict__ rowss)
{
    __shared__ float red[256];
    int bid = blockIdx.x;                       // n*K + k
    int k = bid & 31;
    float sv = ssum[bid];
    float v = up[(size_t)bid * C_ + threadIdx.x] - sv * cent[k * C_ + threadIdx.x];
    red[threadIdx.x] = v * v; __syncthreads();
    for (int st = 128; st > 0; st >>= 1) {
        if (threadIdx.x < st) red[threadIdx.x] += red[threadIdx.x + st];
        __syncthreads();
    }
    float ss = red[0];
    float ri = 1.0f / fmaxf(sqrtf(ss), 1e-12f);
    upn[(size_t)bid * C_ + threadIdx.x] = v * ri;
    if (threadIdx.x == 0) rowss[bid] = ss * ri * ri;
}

// ---------- K7: global l2norm + FC, one block per output channel c ----------
__global__ __launch_bounds__(256) void k_fc(
    const float* __restrict__ upn, const float* __restrict__ rowss,
    const float* __restrict__ w, const float* __restrict__ b,
    float* __restrict__ upvec)
{
    __shared__ float rnb[16];
    __shared__ float red[16][5];
    int c = blockIdx.x;                         // 256
    int tid = threadIdx.x;
    int wv = tid >> 6, lane = tid & 63;
    if (tid < 16) {
        float ts = 0.f;
#pragma unroll
        for (int k = 0; k < K_; ++k) ts += rowss[(tid << 5) + k];
        rnb[tid] = 1.0f / fmaxf(sqrtf(ts), 1e-12f);
    }
    float acc[16];
#pragma unroll
    for (int n = 0; n < 16; ++n) acc[n] = 0.f;
    const float* wr = w + (size_t)c * KC_;
#pragma unroll
    for (int g = 0; g < 8; ++g) {
        int kc = (g << 10) + (tid << 2);
        float4 w4 = *(const float4*)(wr + kc);
#pragma unroll
        for (int n = 0; n < 16; ++n) {
            float4 u4 = *(const float4*)(upn + n * KC_ + kc);
            acc[n] += w4.x * u4.x + w4.y * u4.y + w4.z * u4.z + w4.w * u4.w;
        }
    }
#pragma unroll
    for (int n = 0; n < 16; ++n) {
        float a = acc[n];
#pragma unroll
        for (int s = 1; s < 64; s <<= 1) a += __shfl_xor(a, s);
        if (lane == 0) red[n][wv] = a;
    }
    __syncthreads();
    if (tid < 16) {
        float v = red[tid][0] + red[tid][1] + red[tid][2] + red[tid][3];
        upvec[tid * C_ + c] = v * rnb[tid] + b[c];
    }
}

// ---------- K8: t1up[n,co] = t1_w[co,256:512] . upvec[n,:] + t1_b[co] ----------
__global__ __launch_bounds__(256) void k_t1up(
    const float* __restrict__ upvec, const float* __restrict__ t1w,
    const float* __restrict__ t1b, float* __restrict__ t1up)
{
    __shared__ float wld[256];
    int co = blockIdx.x;                        // 256
    int tid = threadIdx.x;
    wld[tid] = t1w[(size_t)co * 512 + 256 + tid];
    __syncthreads();
    int n = tid >> 4, s = tid & 15;
    float a = 0.f;
#pragma unroll
    for (int i = 0; i < 16; ++i)
        a += wld[s + (i << 4)] * upvec[n * C_ + s + (i << 4)];
#pragma unroll
    for (int st = 1; st < 16; st <<= 1) a += __shfl_xor(a, st);
    if (s == 0) t1up[n * C_ + co] = a + t1b[co];
}

// ---------- K9: MFMA gemm1, pipelined LDS-staged B from fp32 feature ----------
// hb[n,l,co] = bf16(relu(f[n,:,l]·t1wb[co,:] + t1up[n,co]))
__global__ __launch_bounds__(256) void k_gemm1(
    const float* __restrict__ f, const unsigned short* __restrict__ wb,
    const float* __restrict__ t1up, unsigned short* __restrict__ hb)
{
    __shared__ __align__(16) unsigned int lsB[2][128 * 20];     // px stride 20 uints (padded)
    int bid = blockIdx.x;                       // 1024 = n(16) x px_b(32) x co_b(2)
    int co_b = bid & 1, px_b = (bid >> 1) & 31, n = bid >> 6;
    int l0 = px_b << 7;
    int tid = threadIdx.x;
    int wv = tid >> 6, lane = tid & 63;
    int r = lane & 15, quad = lane >> 4;
    int pxl = (wv >> 1) << 6;                   // block-local px base for wave
    int co0 = (co_b << 7) + ((wv & 1) << 6);
    const float* fb_ = f + (size_t)n * CL_ + l0;
    int c2 = tid & 15, pxg = tid >> 4;          // item 0; item 1 = +256 -> pxg+16

    unsigned int pk[2][4];
#pragma unroll
    for (int k2 = 0; k2 < 2; ++k2) {
        const float* s0 = fb_ + (size_t)(c2 << 1) * L_ + ((pxg + (k2 << 4)) << 2);
        float4 a = *(const float4*)s0;
        float4 b = *(const float4*)(s0 + L_);
        pk[k2][0] = pack2(a.x, b.x); pk[k2][1] = pack2(a.y, b.y);
        pk[k2][2] = pack2(a.z, b.z); pk[k2][3] = pack2(a.w, b.w);
    }
    f32x4 acc[4][4];
#pragma unroll
    for (int i = 0; i < 4; ++i)
#pragma unroll
        for (int j = 0; j < 4; ++j) acc[i][j] = (f32x4){0.f, 0.f, 0.f, 0.f};

    for (int i = 0; i < 8; ++i) {
        int c0 = i << 5;
        unsigned int* buf = lsB[i & 1];
#pragma unroll
        for (int k2 = 0; k2 < 2; ++k2) {
            int base = (pxg + (k2 << 4)) * 80 + c2;     // 4 px * 20-uint stride
            buf[base]      = pk[k2][0];
            buf[base + 20] = pk[k2][1];
            buf[base + 40] = pk[k2][2];
            buf[base + 60] = pk[k2][3];
        }
        __syncthreads();
        if (i < 7) {
#pragma unroll
            for (int k2 = 0; k2 < 2; ++k2) {
                const float* s0 = fb_ + (size_t)(c0 + 32 + (c2 << 1)) * L_ + ((pxg + (k2 << 4)) << 2);
                float4 a = *(const float4*)s0;
                float4 b = *(const float4*)(s0 + L_);
                pk[k2][0] = pack2(a.x, b.x); pk[k2][1] = pack2(a.y, b.y);
                pk[k2][2] = pack2(a.z, b.z); pk[k2][3] = pack2(a.w, b.w);
            }
        }
        short8 A[4], B[4];
#pragma unroll
        for (int t = 0; t < 4; ++t)
            A[t] = *(const short8*)(wb + (size_t)(co0 + (t << 4) + r) * C_ + c0 + (quad << 3));
#pragma unroll
        for (int t = 0; t < 4; ++t)
            B[t] = *(const short8*)((const unsigned short*)buf + (pxl + (t << 4) + r) * 40 + (quad << 3));
#pragma unroll
        for (int pxt = 0; pxt < 4; ++pxt)
#pragma unroll
            for (int cot = 0; cot < 4; ++cot)
                acc[pxt][cot] = __builtin_amdgcn_mfma_f32_16x16x32_bf16(A[cot], B[pxt], acc[pxt][cot], 0, 0, 0);
    }
#pragma unroll
    for (int pxt = 0; pxt < 4; ++pxt) {
        int px = l0 + pxl + (pxt << 4) + r;
        unsigned short* orow = hb + ((size_t)n * L_ + px) * C_;
#pragma unroll
        for (int cot = 0; cot < 4; ++cot) {
            int cb = co0 + (cot << 4) + (quad << 2);
            float4 bb = *(const float4*)(t1up + n * C_ + cb);
            unsigned int p0 = pack2(fmaxf(acc[pxt][cot][0] + bb.x, 0.f),
                                    fmaxf(acc[pxt][cot][1] + bb.y, 0.f));
            unsigned int p1 = pack2(fmaxf(acc[pxt][cot][2] + bb.z, 0.f),
                                    fmaxf(acc[pxt][cot][3] + bb.w, 0.f));
            *(uint2*)(orow + cb) = make_uint2(p0, p1);
        }
    }
}

// ---------- K10: MFMA gemm2, pipelined LDS-staged B from hb ----------
// out[n,co,l] = relu(hb[n,l,:]·t2wb[co,:] + t2b[co])
__global__ __launch_bounds__(256) void k_gemm2(
    const unsigned short* __restrict__ hb, const unsigned short* __restrict__ wb,
    const float* __restrict__ t2b, float* __restrict__ out)
{
    __shared__ __align__(16) unsigned short lsB[2][128 * 40];   // px stride 40 ushorts (padded)
    int bid = blockIdx.x;                       // 1024
    int co_b = bid & 1, px_b = (bid >> 1) & 31, n = bid >> 6;
    int l0 = px_b << 7;
    int tid = threadIdx.x;
    int wv = tid >> 6, lane = tid & 63;
    int r = lane & 15, quad = lane >> 4;
    int pxl = (wv >> 1) << 6;
    int co0 = (co_b << 7) + ((wv & 1) << 6);
    const unsigned short* hrow = hb + ((size_t)n * L_ + l0) * C_;
    int q = tid & 3, pxs = tid >> 2;            // item 0: px = pxs; item 1: px = pxs+64

    uint4 pre[2];
#pragma unroll
    for (int k2 = 0; k2 < 2; ++k2)
        pre[k2] = *(const uint4*)(hrow + (size_t)(pxs + (k2 << 6)) * C_ + (q << 3));

    f32x4 acc[4][4];
#pragma unroll
    for (int i = 0; i < 4; ++i)
#pragma unroll
        for (int j = 0; j < 4; ++j) acc[i][j] = (f32x4){0.f, 0.f, 0.f, 0.f};

    for (int i = 0; i < 8; ++i) {
        int c0 = i << 5;
        unsigned short* buf = lsB[i & 1];
#pragma unroll
        for (int k2 = 0; k2 < 2; ++k2)
            *(uint4*)(buf + (pxs + (k2 << 6)) * 40 + (q << 3)) = pre[k2];
        __syncthreads();
        if (i < 7) {
#pragma unroll
            for (int k2 = 0; k2 < 2; ++k2)
                pre[k2] = *(const uint4*)(hrow + (size_t)(pxs + (k2 << 6)) * C_ + c0 + 32 + (q << 3));
        }
        short8 A[4], B[4];
#pragma unroll
        for (int t = 0; t < 4; ++t)
            A[t] = *(const short8*)(wb + (size_t)(co0 + (t << 4) + r) * C_ + c0 + (quad << 3));
#pragma unroll
        for (int t = 0; t < 4; ++t)
            B[t] = *(const short8*)(buf + (pxl + (t << 4) + r) * 40 + (quad << 3));
#pragma unroll
        for (int pxt = 0; pxt < 4; ++pxt)
#pragma unroll
            for (int cot = 0; cot < 4; ++cot)
                acc[pxt][cot] = __builtin_amdgcn_mfma_f32_16x16x32_bf16(A[cot], B[pxt], acc[pxt][cot], 0, 0, 0);
    }
#pragma unroll
    for (int pxt = 0; pxt < 4; ++pxt) {
        int px = l0 + pxl + (pxt << 4) + r;
#pragma unroll
        for (int cot = 0; cot < 4; ++cot) {
            int cb = co0 + (cot << 4) + (quad << 2);
            float4 bb = *(const float4*)(t2b + cb);
            out[((size_t)n * C_ + cb + 0) * L_ + px] = fmaxf(acc[pxt][cot][0] + bb.x, 0.f);
            out[((size_t)n * C_ + cb + 1) * L_ + px] = fmaxf(acc[pxt][cot][1] + bb.y, 0.f);
            out[((size_t)n * C_ + cb + 2) * L_ + px] = fmaxf(acc[pxt][cot][2] + bb.z, 0.f);
            out[((size_t)n * C_ + cb + 3) * L_ + px] = fmaxf(acc[pxt][cot][3] + bb.w, 0.f);
        }
    }
}

extern "C" void kernel_launch(void* const* d_in, const int* in_sizes, int n_in,
                              void* d_out, int out_size, void* d_ws, size_t ws_size,
                              hipStream_t stream)
{
    const float* feature = (const float*)d_in[0];
    const float* conv_w  = (const float*)d_in[1];
    const float* conv_b  = (const float*)d_in[2];
    const float* cent    = (const float*)d_in[3];
    const float* upfc_w  = (const float*)d_in[4];
    const float* upfc_b  = (const float*)d_in[5];
    const float* t1w     = (const float*)d_in[6];
    const float* t1b     = (const float*)d_in[7];
    const float* t2w     = (const float*)d_in[8];
    const float* t2b     = (const float*)d_in[9];

    float* ws = (float*)d_ws;                    // 43.3 MB total
    unsigned short* xnb = (unsigned short*)ws;           // 16777216 us (32 MB)
    unsigned short* hb  = xnb;                           // alias: xnb dead after k_conv
    float* rest  = ws + 8388608;
    float* rinv  = rest;                         // 65536
    float* sa    = rinv + 65536;                 // 2097152 (8 MB)
    float* up    = sa + 2097152;                 // 131072
    float* ssum  = up + 131072;                  // 512
    float* upn   = ssum + 512;                   // 131072
    float* rowss = upn + 131072;                 // 512
    float* upvec = rowss + 512;                  // 4096
    float* t1up  = upvec + 4096;                 // 4096
    unsigned short* wbconv = (unsigned short*)upn;       // alias: upn written later by k_rowfix
    unsigned short* t1wb = (unsigned short*)sa;          // alias: sa dead after k_einsum
    unsigned short* t2wb = t1wb + 65536;
    float* out = (float*)d_out;

    hipMemsetAsync(up, 0, 131072 * sizeof(float), stream);
    k_prep     <<<2048, 256, 0, stream>>>(feature, rinv, xnb);
    k_wpack    <<<288,  256, 0, stream>>>(conv_w, wbconv);
    k_conv     <<<1024, 256, 0, stream>>>(xnb, wbconv, conv_b, sa);
    k_ssum     <<<512,  256, 0, stream>>>(sa, ssum);
    k_einsum   <<<512,  256, 0, stream>>>(feature, rinv, sa, up);
    k_rowfix   <<<512,  256, 0, stream>>>(up, ssum, cent, upn, rowss);
    k_wpack2   <<<256,  256, 0, stream>>>(t1w, 512, t1wb);
    k_wpack2   <<<256,  256, 0, stream>>>(t2w, 256, t2wb);
    k_fc       <<<256,  256, 0, stream>>>(upn, rowss, upfc_w, upfc_b, upvec);
    k_t1up     <<<256,  256, 0, stream>>>(upvec, t1w, t1b, t1up);
    k_gemm1    <<<1024, 256, 0, stream>>>(feature, t1wb, t1up, hb);
    k_gemm2    <<<1024, 256, 0, stream>>>(hb, t2wb, t2b, out);
}

// Round 4
// 341.935 us; speedup vs baseline: 1.2213x; 1.0297x over previous
//
#include <hip/hip_runtime.h>
#include <cstdint>

#define N_ 16
#define C_ 256
#define H_ 64
#define W_ 64
#define L_ 4096          // H*W
#define K_ 32
#define CL_ (C_*L_)      // 1048576
#define KL_ (K_*L_)      // 131072
#define KC_ (K_*C_)      // 8192

typedef __attribute__((ext_vector_type(8))) short short8;   // 8 bf16 (4 VGPRs)
typedef __attribute__((ext_vector_type(4))) float f32x4;    // MFMA C/D frag

__device__ __forceinline__ unsigned short f2bf(float x) {   // RNE fp32->bf16
    unsigned int u = __float_as_uint(x);
    u += 0x7fffu + ((u >> 16) & 1u);
    return (unsigned short)(u >> 16);
}
__device__ __forceinline__ unsigned int pack2(float a, float b) {
    return (unsigned int)f2bf(a) | ((unsigned int)f2bf(b) << 16);
}

// ---------- K1: fused rinv + xn(bf16) transposed to (n,l,c) ----------
__global__ __launch_bounds__(256) void k_prep(
    const float* __restrict__ f, float* __restrict__ rinv,
    unsigned short* __restrict__ xnb)
{
    __shared__ float tile[256 * 34];            // [c][l], stride 34 (conflict-free)
    __shared__ float ssred[8 * 33];
    __shared__ float rbuf[32];
    int bid = blockIdx.x;
    int n = bid >> 7;
    int l0 = (bid & 127) << 5;
    int tid = threadIdx.x;
    int l = tid & 31, cb = tid >> 5;            // cb 0..7
    const float* fp = f + (size_t)n * CL_ + l0 + l;
    float ss = 0.f;
#pragma unroll
    for (int i = 0; i < 32; ++i) {
        int c = (cb << 5) + i;
        float v = fp[(size_t)c * L_];
        tile[c * 34 + l] = v;
        ss = fmaf(v, v, ss);
    }
    ssred[cb * 33 + l] = ss;
    __syncthreads();
    if (tid < 32) {
        float s = 0.f;
#pragma unroll
        for (int j = 0; j < 8; ++j) s += ssred[j * 33 + tid];
        float ri = 1.0f / fmaxf(sqrtf(s), 1e-12f);
        rinv[n * L_ + l0 + tid] = ri;
        rbuf[tid] = ri;
    }
    __syncthreads();
    float ri = rbuf[l];
    unsigned short* op = xnb + ((size_t)n * L_ + l0 + l) * C_ + (cb << 5);
#pragma unroll
    for (int g = 0; g < 4; ++g) {
        unsigned int pk[4];
#pragma unroll
        for (int d = 0; d < 4; ++d) {
            int c = (cb << 5) + (g << 3) + (d << 1);
            pk[d] = pack2(tile[c * 34 + l] * ri, tile[(c + 1) * 34 + l] * ri);
        }
        *(uint4*)(op + (g << 3)) = make_uint4(pk[0], pk[1], pk[2], pk[3]);
    }
}

// ---------- K2: repack conv weights -> wb[t][ch][q][k][8] bf16 ----------
// New layout: linear = ((t*8 + ch)*4 + q)*256 + k*8 + j, where c = ch*32+q*8+j.
// A-fragment load for lane (r,quad) becomes wb + ((t*8+ch)*4+quad)*256 + r*8:
// consecutive r lanes are CONTIGUOUS 16B -> 4x256B segments per instruction
// (was 16x64B segments with the old [t][k][c] layout).
__global__ __launch_bounds__(256) void k_wpack(const float* __restrict__ w, unsigned short* __restrict__ wb) {
    int i = blockIdx.x * 256 + threadIdx.x;     // 73728 = 9*8*4*256
    int j = i & 7;
    int k = (i >> 3) & 31;
    int q = (i >> 8) & 3;
    int ch = (i >> 10) & 7;
    int t = i >> 13;
    int c = (ch << 5) + (q << 3) + j;
    wb[i] = f2bf(w[k * 2304 + c * 9 + t]);
}

// ---------- generic 256x256 weight pack (row stride in floats) ----------
__global__ __launch_bounds__(256) void k_wpack2(const float* __restrict__ w, int stride,
                                                unsigned short* __restrict__ wb) {
    int i = blockIdx.x * 256 + threadIdx.x;     // 65536
    int co = i >> 8, ci = i & 255;
    wb[i] = f2bf(w[(size_t)co * stride + ci]);
}

// ---------- K3: double-buffered MFMA 3x3 conv + fused softmax ----------
// r3 structure (proven clean: WRITE 12 MB, FETCH 17 MB, XCD swizzle) with the
// weight path rebuilt: (a) repacked wb -> each A load is 4x256B contiguous
// segments; (b) per-tap-row BATCHED loads (6 A-frags + 3 B-frags issued as a
// group, all static indices) -> ~12-deep MLP instead of the VGPR-52 serial
// load->wait->mfma chain that made each chunk ~5.8K cy with all pipes <5%.
__global__ __launch_bounds__(256, 4) void k_conv(
    const unsigned short* __restrict__ xnb, const unsigned short* __restrict__ wb,
    const float* __restrict__ bias, float* __restrict__ sa)
{
    __shared__ __align__(16) unsigned short lsB[2][3 * 66 * 40];   // 2 x 15840 B
    int bid = blockIdx.x;
    int n = bid & 15, y = bid >> 4;             // XCD-locality swizzle (r3-proven)
    int tid = threadIdx.x;
    int wv = tid >> 6, lane = tid & 63;
    int r = lane & 15, quad = lane >> 4;
    int pxw = (wv << 4) + r;                    // this lane's output x
    const unsigned short* xb = xnb + (size_t)n * CL_;

    // staging plan: 3 rows x 66 px x 4 quads = 792 uint4 items, 3-4 per thread
    const unsigned short* sptr[4];
    int sidx[4];
    bool svalid[4];
    int scnt = (tid < 24) ? 4 : 3;
#pragma unroll
    for (int k = 0; k < 4; ++k) {
        int j = tid + (k << 8);
        int row = j / 264; if (row > 2) row = 2;
        int rem = j - row * 264;
        int px = rem >> 2, q = rem & 3;
        int yy = y + row - 1, xx = px - 1;
        bool ok = ((unsigned)yy < 64u) && ((unsigned)xx < 64u);
        int yc = ok ? yy : 0, xc = ok ? xx : 0;
        sptr[k] = xb + (((size_t)(yc << 6) + xc) << 8) + (q << 3);
        svalid[k] = ok;
        sidx[k] = (row * 66 + px) * 40 + (q << 3);
    }
    const uint4 z4 = make_uint4(0, 0, 0, 0);
    uint4 pre[4];
#pragma unroll
    for (int k = 0; k < 4; ++k)
        pre[k] = (k < scnt && svalid[k]) ? *(const uint4*)sptr[k] : z4;

    // wave-invariant weight base for this lane: + r*8 within each 256-short panel
    const unsigned short* wlane = wb + (quad << 8) + (r << 3);

    f32x4 acc0 = (f32x4){0.f, 0.f, 0.f, 0.f};
    f32x4 acc1 = (f32x4){0.f, 0.f, 0.f, 0.f};
    for (int i = 0; i < 8; ++i) {
        int c0 = i << 5;
        unsigned short* buf = lsB[i & 1];
#pragma unroll
        for (int k = 0; k < 4; ++k)
            if (k < scnt) *(uint4*)(buf + sidx[k]) = pre[k];
        __syncthreads();                        // single barrier/chunk
        if (i < 7) {
#pragma unroll
            for (int k = 0; k < 4; ++k)
                pre[k] = (k < scnt && svalid[k]) ? *(const uint4*)(sptr[k] + c0 + 32) : z4;
        }
        // panel index for (t, chunk i): ((t*8 + i)*4 + quad)*256
#pragma unroll
        for (int dy = 0; dy < 3; ++dy) {
            short8 A0r[3], A1r[3], Br[3];
#pragma unroll
            for (int dx = 0; dx < 3; ++dx) {
                int t = dy * 3 + dx;
                const unsigned short* wp = wlane + (((t << 3) + i) << 10);  // (t*8+i)*4*256
                A0r[dx] = *(const short8*)wp;             // k = r
                A1r[dx] = *(const short8*)(wp + 128);     // k = 16 + r
                Br[dx]  = *(const short8*)(buf + (dy * 66 + pxw + dx) * 40 + (quad << 3));
            }
#pragma unroll
            for (int dx = 0; dx < 3; ++dx) {
                acc0 = __builtin_amdgcn_mfma_f32_16x16x32_bf16(A0r[dx], Br[dx], acc0, 0, 0, 0);
                acc1 = __builtin_amdgcn_mfma_f32_16x16x32_bf16(A1r[dx], Br[dx], acc1, 0, 0, 0);
            }
        }
    }
    // bias + softmax over k (32 values per px: 4 quads x 8 regs)
    float4 b0 = *(const float4*)(bias + (quad << 2));
    float4 b1 = *(const float4*)(bias + 16 + (quad << 2));
    float v[8];
    v[0] = acc0[0] + b0.x; v[1] = acc0[1] + b0.y; v[2] = acc0[2] + b0.z; v[3] = acc0[3] + b0.w;
    v[4] = acc1[0] + b1.x; v[5] = acc1[1] + b1.y; v[6] = acc1[2] + b1.z; v[7] = acc1[3] + b1.w;
    float mx = v[0];
#pragma unroll
    for (int j = 1; j < 8; ++j) mx = fmaxf(mx, v[j]);
    mx = fmaxf(mx, __shfl_xor(mx, 16));
    mx = fmaxf(mx, __shfl_xor(mx, 32));
    float s = 0.f;
#pragma unroll
    for (int j = 0; j < 8; ++j) { v[j] = __expf(v[j] - mx); s += v[j]; }
    s += __shfl_xor(s, 16);
    s += __shfl_xor(s, 32);
    float rs = 1.0f / s;
    int l = (y << 6) + pxw;
    float* sp = sa + (size_t)n * KL_ + l;
#pragma unroll
    for (int j = 0; j < 4; ++j) {
        sp[(size_t)((quad << 2) + j) * L_] = v[j] * rs;
        sp[(size_t)(16 + (quad << 2) + j) * L_] = v[4 + j] * rs;
    }
}

// ---------- K4: ssum[n,k] = sum_l sa[n,k,l] ----------
__global__ __launch_bounds__(256) void k_ssum(const float* __restrict__ sa, float* __restrict__ ssum) {
    __shared__ float red[256];
    int bid = blockIdx.x;                       // n*K + k
    const float* sp = sa + (size_t)bid * L_;
    float s = 0.f;
    for (int m = 0; m < 16; ++m) s += sp[threadIdx.x + (m << 8)];
    red[threadIdx.x] = s; __syncthreads();
    for (int st = 128; st > 0; st >>= 1) {
        if (threadIdx.x < st) red[threadIdx.x] += red[threadIdx.x + st];
        __syncthreads();
    }
    if (threadIdx.x == 0) ssum[bid] = red[0];
}

// ---------- K5: up[n,k,c] += sum_l sa[n,k,l] * xn[n,c,l] ----------
__global__ __launch_bounds__(256) void k_einsum(
    const float* __restrict__ f, const float* __restrict__ rinv,
    const float* __restrict__ sa, float* __restrict__ up)
{
    __shared__ float xn_s[C_ * 33];
    __shared__ float sa_s[K_ * 32];
    int bid = blockIdx.x;                       // 512
    int n = bid >> 5;
    int l0 = (bid & 31) << 7;
    int tid = threadIdx.x;
    int kq = tid >> 5, cq = tid & 31;
    float acc[4][8];
#pragma unroll
    for (int i = 0; i < 4; ++i)
#pragma unroll
        for (int j = 0; j < 8; ++j) acc[i][j] = 0.f;

    for (int ch = 0; ch < 4; ++ch) {
        int lc = l0 + (ch << 5);
        __syncthreads();
        {
            int crow = tid >> 3, lq = (tid & 7) << 2;
#pragma unroll
            for (int p = 0; p < 8; ++p) {
                int c = (p << 5) + crow;
                float4 f4 = *(const float4*)(f + (size_t)n * CL_ + (size_t)c * L_ + lc + lq);
                float4 r4 = *(const float4*)(rinv + n * L_ + lc + lq);
                float* d = xn_s + c * 33 + lq;
                d[0] = f4.x * r4.x; d[1] = f4.y * r4.y; d[2] = f4.z * r4.z; d[3] = f4.w * r4.w;
            }
        }
        {
            int k = tid >> 3, lq = (tid & 7) << 2;
            float4 a4 = *(const float4*)(sa + (size_t)n * KL_ + (size_t)k * L_ + lc + lq);
            *(float4*)(sa_s + (k << 5) + lq) = a4;
        }
        __syncthreads();
#pragma unroll 4
        for (int l = 0; l < 32; ++l) {
            float sv[4], xv[8];
#pragma unroll
            for (int i = 0; i < 4; ++i) sv[i] = sa_s[((kq << 2) + i) * 32 + l];
#pragma unroll
            for (int j = 0; j < 8; ++j) xv[j] = xn_s[(cq + (j << 5)) * 33 + l];
#pragma unroll
            for (int i = 0; i < 4; ++i)
#pragma unroll
                for (int j = 0; j < 8; ++j) acc[i][j] = fmaf(sv[i], xv[j], acc[i][j]);
        }
    }
    float* upp = up + (size_t)n * KC_;
#pragma unroll
    for (int i = 0; i < 4; ++i)
#pragma unroll
        for (int j = 0; j < 8; ++j)
            atomicAdd(upp + ((kq << 2) + i) * C_ + cq + (j << 5), acc[i][j]);
}

// ---------- K6: subtract centroid term, l2norm rows, record row sumsq ----------
__global__ __launch_bounds__(256) void k_rowfix(
    const float* __restrict__ up, const float* __restrict__ ssum,
    const float* __restrict__ cent, float* __restrict__ upn, float* __restrict__ rowss)
{
    __shared__ float red[256];
    int bid = blockIdx.x;                       // n*K + k
    int k = bid & 31;
    float sv = ssum[bid];
    float v = up[(size_t)bid * C_ + threadIdx.x] - sv * cent[k * C_ + threadIdx.x];
    red[threadIdx.x] = v * v; __syncthreads();
    for (int st = 128; st > 0; st >>= 1) {
        if (threadIdx.x < st) red[threadIdx.x] += red[threadIdx.x + st];
        __syncthreads();
    }
    float ss = red[0];
    float ri = 1.0f / fmaxf(sqrtf(ss), 1e-12f);
    upn[(size_t)bid * C_ + threadIdx.x] = v * ri;
    if (threadIdx.x == 0) rowss[bid] = ss * ri * ri;
}

// ---------- K7: global l2norm + FC, one block per output channel c ----------
__global__ __launch_bounds__(256) void k_fc(
    const float* __restrict__ upn, const float* __restrict__ rowss,
    const float* __restrict__ w, const float* __restrict__ b,
    float* __restrict__ upvec)
{
    __shared__ float rnb[16];
    __shared__ float red[16][5];
    int c = blockIdx.x;                         // 256
    int tid = threadIdx.x;
    int wv = tid >> 6, lane = tid & 63;
    if (tid < 16) {
        float ts = 0.f;
#pragma unroll
        for (int k = 0; k < K_; ++k) ts += rowss[(tid << 5) + k];
        rnb[tid] = 1.0f / fmaxf(sqrtf(ts), 1e-12f);
    }
    float acc[16];
#pragma unroll
    for (int n = 0; n < 16; ++n) acc[n] = 0.f;
    const float* wr = w + (size_t)c * KC_;
#pragma unroll
    for (int g = 0; g < 8; ++g) {
        int kc = (g << 10) + (tid << 2);
        float4 w4 = *(const float4*)(wr + kc);
#pragma unroll
        for (int n = 0; n < 16; ++n) {
            float4 u4 = *(const float4*)(upn + n * KC_ + kc);
            acc[n] += w4.x * u4.x + w4.y * u4.y + w4.z * u4.z + w4.w * u4.w;
        }
    }
#pragma unroll
    for (int n = 0; n < 16; ++n) {
        float a = acc[n];
#pragma unroll
        for (int s = 1; s < 64; s <<= 1) a += __shfl_xor(a, s);
        if (lane == 0) red[n][wv] = a;
    }
    __syncthreads();
    if (tid < 16) {
        float v = red[tid][0] + red[tid][1] + red[tid][2] + red[tid][3];
        upvec[tid * C_ + c] = v * rnb[tid] + b[c];
    }
}

// ---------- K8: t1up[n,co] = t1_w[co,256:512] . upvec[n,:] + t1_b[co] ----------
__global__ __launch_bounds__(256) void k_t1up(
    const float* __restrict__ upvec, const float* __restrict__ t1w,
    const float* __restrict__ t1b, float* __restrict__ t1up)
{
    __shared__ float wld[256];
    int co = blockIdx.x;                        // 256
    int tid = threadIdx.x;
    wld[tid] = t1w[(size_t)co * 512 + 256 + tid];
    __syncthreads();
    int n = tid >> 4, s = tid & 15;
    float a = 0.f;
#pragma unroll
    for (int i = 0; i < 16; ++i)
        a += wld[s + (i << 4)] * upvec[n * C_ + s + (i << 4)];
#pragma unroll
    for (int st = 1; st < 16; st <<= 1) a += __shfl_xor(a, st);
    if (s == 0) t1up[n * C_ + co] = a + t1b[co];
}

// ---------- K9: MFMA gemm1, pipelined LDS-staged B from fp32 feature ----------
// hb[n,l,co] = bf16(relu(f[n,:,l]·t1wb[co,:] + t1up[n,co]))
__global__ __launch_bounds__(256) void k_gemm1(
    const float* __restrict__ f, const unsigned short* __restrict__ wb,
    const float* __restrict__ t1up, unsigned short* __restrict__ hb)
{
    __shared__ __align__(16) unsigned int lsB[2][128 * 20];     // px stride 20 uints (padded)
    int bid = blockIdx.x;                       // 1024 = n(16) x px_b(32) x co_b(2)
    int co_b = bid & 1, px_b = (bid >> 1) & 31, n = bid >> 6;
    int l0 = px_b << 7;
    int tid = threadIdx.x;
    int wv = tid >> 6, lane = tid & 63;
    int r = lane & 15, quad = lane >> 4;
    int pxl = (wv >> 1) << 6;                   // block-local px base for wave
    int co0 = (co_b << 7) + ((wv & 1) << 6);
    const float* fb_ = f + (size_t)n * CL_ + l0;
    int c2 = tid & 15, pxg = tid >> 4;          // item 0; item 1 = +256 -> pxg+16

    unsigned int pk[2][4];
#pragma unroll
    for (int k2 = 0; k2 < 2; ++k2) {
        const float* s0 = fb_ + (size_t)(c2 << 1) * L_ + ((pxg + (k2 << 4)) << 2);
        float4 a = *(const float4*)s0;
        float4 b = *(const float4*)(s0 + L_);
        pk[k2][0] = pack2(a.x, b.x); pk[k2][1] = pack2(a.y, b.y);
        pk[k2][2] = pack2(a.z, b.z); pk[k2][3] = pack2(a.w, b.w);
    }
    f32x4 acc[4][4];
#pragma unroll
    for (int i = 0; i < 4; ++i)
#pragma unroll
        for (int j = 0; j < 4; ++j) acc[i][j] = (f32x4){0.f, 0.f, 0.f, 0.f};

    for (int i = 0; i < 8; ++i) {
        int c0 = i << 5;
        unsigned int* buf = lsB[i & 1];
#pragma unroll
        for (int k2 = 0; k2 < 2; ++k2) {
            int base = (pxg + (k2 << 4)) * 80 + c2;     // 4 px * 20-uint stride
            buf[base]      = pk[k2][0];
            buf[base + 20] = pk[k2][1];
            buf[base + 40] = pk[k2][2];
            buf[base + 60] = pk[k2][3];
        }
        __syncthreads();
        if (i < 7) {
#pragma unroll
            for (int k2 = 0; k2 < 2; ++k2) {
                const float* s0 = fb_ + (size_t)(c0 + 32 + (c2 << 1)) * L_ + ((pxg + (k2 << 4)) << 2);
                float4 a = *(const float4*)s0;
                float4 b = *(const float4*)(s0 + L_);
                pk[k2][0] = pack2(a.x, b.x); pk[k2][1] = pack2(a.y, b.y);
                pk[k2][2] = pack2(a.z, b.z); pk[k2][3] = pack2(a.w, b.w);
            }
        }
        short8 A[4], B[4];
#pragma unroll
        for (int t = 0; t < 4; ++t)
            A[t] = *(const short8*)(wb + (size_t)(co0 + (t << 4) + r) * C_ + c0 + (quad << 3));
#pragma unroll
        for (int t = 0; t < 4; ++t)
            B[t] = *(const short8*)((const unsigned short*)buf + (pxl + (t << 4) + r) * 40 + (quad << 3));
#pragma unroll
        for (int pxt = 0; pxt < 4; ++pxt)
#pragma unroll
            for (int cot = 0; cot < 4; ++cot)
                acc[pxt][cot] = __builtin_amdgcn_mfma_f32_16x16x32_bf16(A[cot], B[pxt], acc[pxt][cot], 0, 0, 0);
    }
#pragma unroll
    for (int pxt = 0; pxt < 4; ++pxt) {
        int px = l0 + pxl + (pxt << 4) + r;
        unsigned short* orow = hb + ((size_t)n * L_ + px) * C_;
#pragma unroll
        for (int cot = 0; cot < 4; ++cot) {
            int cb = co0 + (cot << 4) + (quad << 2);
            float4 bb = *(const float4*)(t1up + n * C_ + cb);
            unsigned int p0 = pack2(fmaxf(acc[pxt][cot][0] + bb.x, 0.f),
                                    fmaxf(acc[pxt][cot][1] + bb.y, 0.f));
            unsigned int p1 = pack2(fmaxf(acc[pxt][cot][2] + bb.z, 0.f),
                                    fmaxf(acc[pxt][cot][3] + bb.w, 0.f));
            *(uint2*)(orow + cb) = make_uint2(p0, p1);
        }
    }
}

// ---------- K10: MFMA gemm2, pipelined LDS-staged B from hb ----------
// out[n,co,l] = relu(hb[n,l,:]·t2wb[co,:] + t2b[co])
__global__ __launch_bounds__(256) void k_gemm2(
    const unsigned short* __restrict__ hb, const unsigned short* __restrict__ wb,
    const float* __restrict__ t2b, float* __restrict__ out)
{
    __shared__ __align__(16) unsigned short lsB[2][128 * 40];   // px stride 40 ushorts (padded)
    int bid = blockIdx.x;                       // 1024
    int co_b = bid & 1, px_b = (bid >> 1) & 31, n = bid >> 6;
    int l0 = px_b << 7;
    int tid = threadIdx.x;
    int wv = tid >> 6, lane = tid & 63;
    int r = lane & 15, quad = lane >> 4;
    int pxl = (wv >> 1) << 6;
    int co0 = (co_b << 7) + ((wv & 1) << 6);
    const unsigned short* hrow = hb + ((size_t)n * L_ + l0) * C_;
    int q = tid & 3, pxs = tid >> 2;            // item 0: px = pxs; item 1: px = pxs+64

    uint4 pre[2];
#pragma unroll
    for (int k2 = 0; k2 < 2; ++k2)
        pre[k2] = *(const uint4*)(hrow + (size_t)(pxs + (k2 << 6)) * C_ + (q << 3));

    f32x4 acc[4][4];
#pragma unroll
    for (int i = 0; i < 4; ++i)
#pragma unroll
        for (int j = 0; j < 4; ++j) acc[i][j] = (f32x4){0.f, 0.f, 0.f, 0.f};

    for (int i = 0; i < 8; ++i) {
        int c0 = i << 5;
        unsigned short* buf = lsB[i & 1];
#pragma unroll
        for (int k2 = 0; k2 < 2; ++k2)
            *(uint4*)(buf + (pxs + (k2 << 6)) * 40 + (q << 3)) = pre[k2];
        __syncthreads();
        if (i < 7) {
#pragma unroll
            for (int k2 = 0; k2 < 2; ++k2)
                pre[k2] = *(const uint4*)(hrow + (size_t)(pxs + (k2 << 6)) * C_ + c0 + 32 + (q << 3));
        }
        short8 A[4], B[4];
#pragma unroll
        for (int t = 0; t < 4; ++t)
            A[t] = *(const short8*)(wb + (size_t)(co0 + (t << 4) + r) * C_ + c0 + (quad << 3));
#pragma unroll
        for (int t = 0; t < 4; ++t)
            B[t] = *(const short8*)(buf + (pxl + (t << 4) + r) * 40 + (quad << 3));
#pragma unroll
        for (int pxt = 0; pxt < 4; ++pxt)
#pragma unroll
            for (int cot = 0; cot < 4; ++cot)
                acc[pxt][cot] = __builtin_amdgcn_mfma_f32_16x16x32_bf16(A[cot], B[pxt], acc[pxt][cot], 0, 0, 0);
    }
#pragma unroll
    for (int pxt = 0; pxt < 4; ++pxt) {
        int px = l0 + pxl + (pxt << 4) + r;
#pragma unroll
        for (int cot = 0; cot < 4; ++cot) {
            int cb = co0 + (cot << 4) + (quad << 2);
            float4 bb = *(const float4*)(t2b + cb);
            out[((size_t)n * C_ + cb + 0) * L_ + px] = fmaxf(acc[pxt][cot][0] + bb.x, 0.f);
            out[((size_t)n * C_ + cb + 1) * L_ + px] = fmaxf(acc[pxt][cot][1] + bb.y, 0.f);
            out[((size_t)n * C_ + cb + 2) * L_ + px] = fmaxf(acc[pxt][cot][2] + bb.z, 0.f);
            out[((size_t)n * C_ + cb + 3) * L_ + px] = fmaxf(acc[pxt][cot][3] + bb.w, 0.f);
        }
    }
}

extern "C" void kernel_launch(void* const* d_in, const int* in_sizes, int n_in,
                              void* d_out, int out_size, void* d_ws, size_t ws_size,
                              hipStream_t stream)
{
    const float* feature = (const float*)d_in[0];
    const float* conv_w  = (const float*)d_in[1];
    const float* conv_b  = (const float*)d_in[2];
    const float* cent    = (const float*)d_in[3];
    const float* upfc_w  = (const float*)d_in[4];
    const float* upfc_b  = (const float*)d_in[5];
    const float* t1w     = (const float*)d_in[6];
    const float* t1b     = (const float*)d_in[7];
    const float* t2w     = (const float*)d_in[8];
    const float* t2b     = (const float*)d_in[9];

    float* ws = (float*)d_ws;                    // 43.3 MB total
    unsigned short* xnb = (unsigned short*)ws;           // 16777216 us (32 MB)
    unsigned short* hb  = xnb;                           // alias: xnb dead after k_conv
    float* rest  = ws + 8388608;
    float* rinv  = rest;                         // 65536
    float* sa    = rinv + 65536;                 // 2097152 (8 MB)
    float* up    = sa + 2097152;                 // 131072
    float* ssum  = up + 131072;                  // 512
    float* upn   = ssum + 512;                   // 131072
    float* rowss = upn + 131072;                 // 512
    float* upvec = rowss + 512;                  // 4096
    float* t1up  = upvec + 4096;                 // 4096
    unsigned short* wbconv = (unsigned short*)upn;       // alias: upn written later by k_rowfix
    unsigned short* t1wb = (unsigned short*)sa;          // alias: sa dead after k_einsum
    unsigned short* t2wb = t1wb + 65536;
    float* out = (float*)d_out;

    hipMemsetAsync(up, 0, 131072 * sizeof(float), stream);
    k_prep     <<<2048, 256, 0, stream>>>(feature, rinv, xnb);
    k_wpack    <<<288,  256, 0, stream>>>(conv_w, wbconv);
    k_conv     <<<1024, 256, 0, stream>>>(xnb, wbconv, conv_b, sa);
    k_ssum     <<<512,  256, 0, stream>>>(sa, ssum);
    k_einsum   <<<512,  256, 0, stream>>>(feature, rinv, sa, up);
    k_rowfix   <<<512,  256, 0, stream>>>(up, ssum, cent, upn, rowss);
    k_wpack2   <<<256,  256, 0, stream>>>(t1w, 512, t1wb);
    k_wpack2   <<<256,  256, 0, stream>>>(t2w, 256, t2wb);
    k_fc       <<<256,  256, 0, stream>>>(upn, rowss, upfc_w, upfc_b, upvec);
    k_t1up     <<<256,  256, 0, stream>>>(upvec, t1w, t1b, t1up);
    k_gemm1    <<<1024, 256, 0, stream>>>(feature, t1wb, t1up, hb);
    k_gemm2    <<<1024, 256, 0, stream>>>(hb, t2wb, t2b, out);
}